// Round 17
// baseline (138.835 us; speedup 1.0000x reference)
//
#include <hip/hip_runtime.h>

// GCN 2-layer + linear head on MI355X.
// R16 post-mortem: agg is at the random-gather FILL ceiling (FETCH 70MB for
// a 12.8MB footprint, ~56% L2 hit; 4MB L2/XCD vs 12.8MB). R17: src-locality
// phase split -- per-node edge lists partitioned into [src<n/2][src>=n/2]
// sub-lists (k_csr key = dstLocal*2+half); agg gathers phase A then B with
// the same accumulators. Instantaneous gather footprint halves to 6.4MB.

typedef float v2f __attribute__((ext_vector_type(2)));

constexpr int NB_SHIFT = 8;                 // 256 nodes per bucket
constexpr int BUCK_NODES = 1 << NB_SHIFT;
constexpr int CAP = 5120;                   // slab cap (worst ~4160 incl selfs+pads)
constexpr int CHUNK = 4096;                 // edges per sort block
constexpr int STPB = 512;
// assumes nbuck <= 512, src < 2^17, padded bucket size <= CAP

// ---- init: slab cursors + dummy bf16 row (replaces hipMemsetAsync) -----
__global__ __launch_bounds__(512) void k_init(int* __restrict__ gcur, int nbuck,
                                              unsigned short* __restrict__ dummyRow) {
    int t = threadIdx.x;
    if (t < nbuck) gcur[t] = 0;
    if (t < 64) dummyRow[t] = 0;
}

// ---- fused: chunk histogram -> slab reserve -> LDS sort -> dense flush -
__global__ __launch_bounds__(STPB) void k_bsort(const int* __restrict__ src,
                                                const int* __restrict__ dst, int E, int nbuck,
                                                int* __restrict__ gcur,
                                                unsigned* __restrict__ packed) {
    __shared__ int shStart[512];
    __shared__ int shCur[512];
    __shared__ int shOff[512];
    __shared__ unsigned stage[CHUNK];
    __shared__ unsigned short sbkt[CHUNK];
    const int tid = threadIdx.x;
    const int base = blockIdx.x * CHUNK;
    const int end = min(base + CHUNK, E);
    // pass A: count buckets in this chunk (LDS atomics)
    shCur[tid] = 0;
    __syncthreads();
    for (int e = base + tid; e < end; e += STPB)
        atomicAdd(&shCur[dst[e] >> NB_SHIFT], 1);
    __syncthreads();
    int v = shCur[tid];
    shStart[tid] = v;
    __syncthreads();
    for (int s = 1; s < 512; s <<= 1) {      // inclusive Hillis-Steele
        int a = (tid >= s) ? shStart[tid - s] : 0;
        __syncthreads();
        shStart[tid] += a;
        __syncthreads();
    }
    int exc = shStart[tid] - v;
    shStart[tid] = exc;
    shCur[tid] = exc;
    // reserve this chunk's span in bucket slabs (one global atomic each)
    if (tid < nbuck) shOff[tid] = tid * CAP + ((v > 0) ? atomicAdd(&gcur[tid], v) : 0);
    __syncthreads();
    // pass B: permute chunk into LDS, bucket-major
    for (int e = base + tid; e < end; e += STPB) {
        int s = src[e];
        int d = dst[e];
        int b = d >> NB_SHIFT;
        int slot = atomicAdd(&shCur[b], 1);
        stage[slot] = ((unsigned)(d & (BUCK_NODES - 1)) << 17) | (unsigned)s;
        sbkt[slot] = (unsigned short)b;
    }
    __syncthreads();
    // pass C: linear flush, same-bucket runs land contiguously
    int cnt = end - base;
    for (int i = tid; i < cnt; i += STPB) {
        int b = sbkt[i];
        packed[shOff[b] + (i - shStart[b])] = stage[i];
    }
}

// ---- per-bucket counting sort by (dstLocal, srcHalf) -> csr slab -------
// 512 keys: key = dstLocal*2 + (src>=nHalf). Self edge appended to its own
// half; each sub-list padded to x2 with dummy index n.
// rowinfo4[node] = (startA, padA, startB, padB); dinv from raw counts.
__global__ __launch_bounds__(512) void k_csr(const unsigned* __restrict__ packed,
                                             const int* __restrict__ gcur, int n,
                                             int* __restrict__ csr, int4* __restrict__ rowinfo,
                                             float* __restrict__ dinv) {
    __shared__ int cnt[512];
    __shared__ int scn[512];
    __shared__ int cur[512];
    __shared__ int st [512];
    const int tid = threadIdx.x;
    const int nHalf = n >> 1;
    const int e0 = blockIdx.x * CAP;
    const int e1 = e0 + gcur[blockIdx.x];     // slab base + raw size
    cnt[tid] = 0;
    __syncthreads();
    for (int e = e0 + tid; e < e1; e += 512) {
        unsigned p = packed[e];
        int key = (int)((p >> 17) << 1) | (((p & 0x1FFFFu) >= (unsigned)nHalf) ? 1 : 0);
        atomicAdd(&cnt[key], 1);
    }
    __syncthreads();
    int v = cnt[tid];                         // raw edges for this key
    int nodeK = blockIdx.x * BUCK_NODES + (tid >> 1);
    bool selfHere = (nodeK < n) && (((nodeK >= nHalf) ? 1 : 0) == (tid & 1));
    int pad = (v + (selfHere ? 1 : 0) + 1) & ~1;   // + self, round to x2
    scn[tid] = pad;
    __syncthreads();
    for (int s = 1; s < 512; s <<= 1) {       // inclusive Hillis-Steele
        int add = (tid >= s) ? scn[tid - s] : 0;
        __syncthreads();
        scn[tid] += add;
        __syncthreads();
    }
    int start = e0 + scn[tid] - pad;
    st[tid] = start;
    cur[tid] = start;
    __syncthreads();
    // scatter raw edges to their (node, half) sub-list
    for (int e = e0 + tid; e < e1; e += 512) {
        unsigned p = packed[e];
        unsigned s = p & 0x1FFFFu;
        int key = (int)((p >> 17) << 1) | ((s >= (unsigned)nHalf) ? 1 : 0);
        int pos = atomicAdd(&cur[key], 1);    // LDS cursor
        csr[pos] = (int)s;                    // dense slab window, L2-hot
    }
    __syncthreads();
    // per key: append self (if in this half), then dummy-pad to sub-list end
    {
        int endK = (tid < 511) ? st[tid + 1] : (e0 + scn[511]);
        int p = cur[tid];                     // == start + raw count
        if (selfHere) csr[p++] = nodeK;
        for (; p < endK; ++p) csr[p] = n;
    }
    // rowinfo + dinv (one thread per node)
    if (tid < BUCK_NODES) {
        int node = blockIdx.x * BUCK_NODES + tid;
        if (node < n) {
            int sA = st[2 * tid], sB = st[2 * tid + 1];
            int eB = (2 * tid + 2 < 512) ? st[2 * tid + 2] : (e0 + scn[511]);
            rowinfo[node] = make_int4(sA, sB - sA, sB, eB - sB);
            dinv[node] = rsqrtf(1.0f + (float)(cnt[2 * tid] + cnt[2 * tid + 1]));
        }
    }
}

// ---- GEMM: gBf[i][f] = bf16((sum_k A[i][k] * W[k][f]) * dinv[i]) -------
// A-row pointer forced to SGPR via readfirstlane -> scalar s_loads,
// v_fmac v,s,v = 1 VALU instr per FMA. (Timed-graph verified: R13/R14/R15.)
__global__ __launch_bounds__(256) void k_gemm64bf(const float* __restrict__ A,
                                                  const float* __restrict__ W,
                                                  const float* __restrict__ dinv,
                                                  unsigned short* __restrict__ out,
                                                  int n) {
    const int lane = threadIdx.x & 63;
    const int wave = threadIdx.x >> 6;
    float wcol[64];
#pragma unroll
    for (int k = 0; k < 64; ++k) wcol[k] = W[k * 64 + lane];
    int base = blockIdx.x * 64;
    for (int r = wave; r < 64; r += 4) {
        int row = base + r;
        if (row >= n) break;
        int urow = __builtin_amdgcn_readfirstlane(row);   // SGPR row index
        const float* Ar = A + (size_t)urow * 64;          // uniform -> s_load path
        float acc = 0.0f;
#pragma unroll
        for (int k = 0; k < 64; ++k) acc = fmaf(Ar[k], wcol[k], acc);
        float val = acc * dinv[urow];
        unsigned u = __float_as_uint(val);
        u = (u + 0x7FFFu + ((u >> 16) & 1u)) >> 16;   // RNE to bf16
        out[(size_t)urow * 64 + lane] = (unsigned short)u;
    }
}

__device__ __forceinline__ v2f bf2(unsigned u) {
    v2f r;
    r.x = __uint_as_float(u << 16);
    r.y = __uint_as_float(u & 0xFFFF0000u);
    return r;
}

// ---- Aggregate: FOUR nodes per wave (16 lanes each); bf16 rows ---------
// lane = 16*s + 8*grp + q. Two sequential gather phases (src halves) into
// the same accumulators; 4-deep unroll per phase. Self-loop is in csr.
// Reduce: 1 halving round (mask 8); float4 epilogue.
template <bool LAST>
__global__ __launch_bounds__(256) void k_aggregate(
    const uint4* __restrict__ g4,
    const int4* __restrict__ rowinfo, const int* __restrict__ csr,
    const float* __restrict__ dinv, const float* __restrict__ bias,
    const float* __restrict__ Wo, const float* __restrict__ bo,
    float* __restrict__ outRow, float* __restrict__ outHead, int n) {
    int w = (blockIdx.x * blockDim.x + threadIdx.x) >> 6;
    int lane = threadIdx.x & 63;
    const int s = lane >> 4;                  // node slot 0..3
    const int grp = (lane >> 3) & 1;          // 0..1
    const int q = lane & 7;                   // 0..7
    int node = 4 * w + s;
    const bool valid = node < n;
    int4 ri = valid ? rowinfo[node] : make_int4(0, 0, 0, 0);
    v2f a0v = {0.f, 0.f}, a1v = {0.f, 0.f}, a2v = {0.f, 0.f}, a3v = {0.f, 0.f};
#pragma unroll 2
    for (int ph = 0; ph < 2; ++ph) {
        const int e = ph ? ri.z : ri.x;
        const int rnds = (ph ? ri.w : ri.y) >> 1;
        int rm = rnds;
        rm = max(rm, __shfl_xor(rm, 16, 64));
        rm = max(rm, __shfl_xor(rm, 32, 64)); // max over 4 slots
        int r = 0;
        for (; r + 4 <= rm; r += 4) {         // 32 edge-rows in flight / wave
            int c0 = csr[e + 2 * r + grp];    // shared base + imm offsets
            int c1 = csr[e + 2 * r + 2 + grp];
            int c2 = csr[e + 2 * r + 4 + grp];
            int c3 = csr[e + 2 * r + 6 + grp];
            int i0 = (r < rnds) ? c0 : n;
            int i1 = (r + 1 < rnds) ? c1 : n;
            int i2 = (r + 2 < rnds) ? c2 : n;
            int i3 = (r + 3 < rnds) ? c3 : n;
            uint4 x0 = g4[(size_t)i0 * 8 + q];
            uint4 x1 = g4[(size_t)i1 * 8 + q];
            uint4 x2 = g4[(size_t)i2 * 8 + q];
            uint4 x3 = g4[(size_t)i3 * 8 + q];
            a0v += bf2(x0.x); a1v += bf2(x0.y); a2v += bf2(x0.z); a3v += bf2(x0.w);
            a0v += bf2(x1.x); a1v += bf2(x1.y); a2v += bf2(x1.z); a3v += bf2(x1.w);
            a0v += bf2(x2.x); a1v += bf2(x2.y); a2v += bf2(x2.z); a3v += bf2(x2.w);
            a0v += bf2(x3.x); a1v += bf2(x3.y); a2v += bf2(x3.z); a3v += bf2(x3.w);
        }
        for (; r < rm; ++r) {                 // tail (<=3 rounds)
            int c0 = csr[e + 2 * r + grp];
            int i0 = (r < rnds) ? c0 : n;
            uint4 x0 = g4[(size_t)i0 * 8 + q];
            a0v += bf2(x0.x); a1v += bf2(x0.y); a2v += bf2(x0.z); a3v += bf2(x0.w);
        }
    }
    // one halving round over grp (mask 8): grp0 ends with feat 8q..8q+3,
    // grp1 with 8q+4..8q+7
    v2f keep0 = grp ? a2v : a0v;
    v2f keep1 = grp ? a3v : a1v;
    v2f send0 = grp ? a0v : a2v;
    v2f send1 = grp ? a1v : a3v;
    keep0.x += __shfl_xor(send0.x, 8, 64);
    keep0.y += __shfl_xor(send0.y, 8, 64);
    keep1.x += __shfl_xor(send1.x, 8, 64);
    keep1.y += __shfl_xor(send1.y, 8, 64);
    const int base = 8 * q + 4 * grp;
    float dv = valid ? dinv[node] : 0.f;
    float4 bb = *(const float4*)&bias[base];
    float4 vv;
    vv.x = fmaxf(fmaf(dv, keep0.x, bb.x), 0.f);
    vv.y = fmaxf(fmaf(dv, keep0.y, bb.y), 0.f);
    vv.z = fmaxf(fmaf(dv, keep1.x, bb.z), 0.f);
    vv.w = fmaxf(fmaf(dv, keep1.y, bb.w), 0.f);
    if constexpr (LAST) {
        float4 ww = *(const float4*)&Wo[base];
        float p = vv.x * ww.x + vv.y * ww.y + vv.z * ww.z + vv.w * ww.w;
#pragma unroll
        for (int m = 1; m <= 8; m <<= 1) p += __shfl_xor(p, m, 64);
        if ((lane & 15) == 0 && valid) outHead[node] = p + bo[0];
    } else {
        if (valid) *(float4*)&outRow[(size_t)node * 64 + base] = vv;
    }
}

extern "C" void kernel_launch(void* const* d_in, const int* in_sizes, int n_in,
                              void* d_out, int out_size, void* d_ws, size_t ws_size,
                              hipStream_t stream) {
    const float* x  = (const float*)d_in[0];
    const int*   ei = (const int*)d_in[1];
    const float* W1 = (const float*)d_in[2];
    const float* b1 = (const float*)d_in[3];
    const float* W2 = (const float*)d_in[4];
    const float* b2 = (const float*)d_in[5];
    const float* Wo = (const float*)d_in[6];
    const float* bo = (const float*)d_in[7];
    float* out = (float*)d_out;

    const int n = in_sizes[0] / 64;
    const int E = in_sizes[1] / 2;
    const int* src = ei;
    const int* dst = ei + E;

    const int nbuck = (n + BUCK_NODES - 1) >> NB_SHIFT;      // 391
    const int nchunks = (E + CHUNK - 1) / CHUNK;             // 306

    char* ws = (char*)d_ws;
    size_t off = 0;
    auto alloc = [&](size_t bytes) -> void* {
        void* p = ws + off;
        off += (bytes + 255) & ~(size_t)255;
        return p;
    };
    const size_t slabBytes = (size_t)nbuck * CAP * 4 + 4096; // 8.0 MB (+over-read slack)
    const size_t hBytes    = (size_t)n * 64 * 4;             // 25.6 MB (fp32 h1)
    const size_t gBytes    = (size_t)(n + 1) * 64 * 2;       // 12.8 MB (bf16 g + dummy)
    float*          dinv    = (float*)alloc((size_t)n * 4);
    int*            gcur    = (int*)alloc((size_t)nbuck * 4);
    int4*           rowinfo = (int4*)alloc((size_t)n * 16);
    int*            csr     = (int*)alloc(slabBytes);
    char*           regionA = (char*)alloc(hBytes > slabBytes ? hBytes : slabBytes);
    unsigned short* gBf     = (unsigned short*)alloc(gBytes);
    unsigned* packed = (unsigned*)regionA;   // dead after k_csr
    float*    bufH   = (float*)regionA;      // h1 (fp32), written from agg1 on

    // ---- init (slab cursors + dummy bf16 row) ----
    k_init<<<1, 512, 0, stream>>>(gcur, nbuck, gBf + (size_t)n * 64);

    // ---- slab counting sort -> (dst, srcHalf)-sorted csr + rowinfo + dinv ----
    k_bsort<<<nchunks, STPB, 0, stream>>>(src, dst, E, nbuck, gcur, packed);
    k_csr<<<nbuck, 512, 0, stream>>>(packed, gcur, n, csr, rowinfo, dinv);

    const int gemmGrid = (n + 63) / 64;
    const int nodeGrid = (n + 15) / 16;      // 4 nodes/wave, 4 waves/block

    // ---- layer 1 ----
    k_gemm64bf<<<gemmGrid, 256, 0, stream>>>(x, W1, dinv, gBf, n);
    k_aggregate<false><<<nodeGrid, 256, 0, stream>>>((const uint4*)gBf, rowinfo, csr,
                                                     dinv, b1, nullptr, nullptr,
                                                     bufH, nullptr, n);
    // ---- layer 2 (head fused into epilogue) ----
    k_gemm64bf<<<gemmGrid, 256, 0, stream>>>(bufH, W2, dinv, gBf, n);
    k_aggregate<true><<<nodeGrid, 256, 0, stream>>>((const uint4*)gBf, rowinfo, csr,
                                                    dinv, b2, Wo, bo,
                                                    nullptr, out, n);
}

// Round 18
// 138.401 us; speedup vs baseline: 1.0031x; 1.0031x over previous
//
#include <hip/hip_runtime.h>

// GCN 2-layer + linear head on MI355X.
// R17 post-mortem: src-phase split regressed (+2.6us; blocks drift, padding
// waste). Reverted. R18: h1 stored as bf16 -- gemm2 read 25.6->12.8MB,
// agg1 store halves. On the s_load GEMM path the bf16 unpack is SALU
// (u<<16 / u&0xFFFF0000 on SGPRs, co-issues with v_fmac) -> VALU unchanged.
// Extra bf16 rounding at h1: absmax ~7e-4..1e-3, under the 1.5e-3 threshold.

typedef float v2f __attribute__((ext_vector_type(2)));

constexpr int NB_SHIFT = 8;                 // 256 nodes per bucket
constexpr int BUCK_NODES = 1 << NB_SHIFT;
constexpr int CAP = 5120;                   // slab cap (max bucket ~3500 + 512 self + pad)
constexpr int CHUNK = 4096;                 // edges per sort block
constexpr int STPB = 512;
// assumes nbuck <= 512, src < 2^17, padded bucket size <= CAP

__device__ __forceinline__ unsigned rne_bf16(float f) {
    unsigned u = __float_as_uint(f);
    return (u + 0x7FFFu + ((u >> 16) & 1u)) >> 16;
}

// ---- init: slab cursors + dummy bf16 row (replaces hipMemsetAsync) -----
__global__ __launch_bounds__(512) void k_init(int* __restrict__ gcur, int nbuck,
                                              unsigned short* __restrict__ dummyRow) {
    int t = threadIdx.x;
    if (t < nbuck) gcur[t] = 0;
    if (t < 64) dummyRow[t] = 0;
}

// ---- fused: chunk histogram -> slab reserve -> LDS sort -> dense flush -
__global__ __launch_bounds__(STPB) void k_bsort(const int* __restrict__ src,
                                                const int* __restrict__ dst, int E, int nbuck,
                                                int* __restrict__ gcur,
                                                unsigned* __restrict__ packed) {
    __shared__ int shStart[512];
    __shared__ int shCur[512];
    __shared__ int shOff[512];
    __shared__ unsigned stage[CHUNK];
    __shared__ unsigned short sbkt[CHUNK];
    const int tid = threadIdx.x;
    const int base = blockIdx.x * CHUNK;
    const int end = min(base + CHUNK, E);
    // pass A: count buckets in this chunk (LDS atomics)
    shCur[tid] = 0;
    __syncthreads();
    for (int e = base + tid; e < end; e += STPB)
        atomicAdd(&shCur[dst[e] >> NB_SHIFT], 1);
    __syncthreads();
    int v = shCur[tid];
    shStart[tid] = v;
    __syncthreads();
    for (int s = 1; s < 512; s <<= 1) {      // inclusive Hillis-Steele
        int a = (tid >= s) ? shStart[tid - s] : 0;
        __syncthreads();
        shStart[tid] += a;
        __syncthreads();
    }
    int exc = shStart[tid] - v;
    shStart[tid] = exc;
    shCur[tid] = exc;
    // reserve this chunk's span in bucket slabs (one global atomic each)
    if (tid < nbuck) shOff[tid] = tid * CAP + ((v > 0) ? atomicAdd(&gcur[tid], v) : 0);
    __syncthreads();
    // pass B: permute chunk into LDS, bucket-major
    for (int e = base + tid; e < end; e += STPB) {
        int s = src[e];
        int d = dst[e];
        int b = d >> NB_SHIFT;
        int slot = atomicAdd(&shCur[b], 1);
        stage[slot] = ((unsigned)(d & (BUCK_NODES - 1)) << 17) | (unsigned)s;
        sbkt[slot] = (unsigned short)b;
    }
    __syncthreads();
    // pass C: linear flush, same-bucket runs land contiguously
    int cnt = end - base;
    for (int i = tid; i < cnt; i += STPB) {
        int b = sbkt[i];
        packed[shOff[b] + (i - shStart[b])] = stage[i];
    }
}

// ---- per-bucket counting sort by dstLocal -> csr slab; appends SELF edge
//      then pads to x2. rowinfo=(start, paddedCount), dinv ---------------
__global__ __launch_bounds__(512) void k_csr(const unsigned* __restrict__ packed,
                                             const int* __restrict__ gcur, int n,
                                             int* __restrict__ csr, int2* __restrict__ rowinfo,
                                             float* __restrict__ dinv) {
    __shared__ int cnt[BUCK_NODES];
    __shared__ int scn[BUCK_NODES];
    __shared__ int cur[BUCK_NODES];
    const int tid = threadIdx.x;
    const int e0 = blockIdx.x * CAP;
    const int e1 = e0 + gcur[blockIdx.x];     // slab base + size
    if (tid < BUCK_NODES) cnt[tid] = 0;
    __syncthreads();
    for (int e = e0 + tid; e < e1; e += 512)
        atomicAdd(&cnt[packed[e] >> 17], 1);
    __syncthreads();
    int v = (tid < BUCK_NODES) ? cnt[tid] : 0;
    int pad = (v + 2) & ~1;                   // v edges + 1 self, rounded to x2
    if (tid < BUCK_NODES) scn[tid] = pad;
    __syncthreads();
    for (int s = 1; s < BUCK_NODES; s <<= 1) {   // inclusive Hillis-Steele
        int add = (tid >= s && tid < BUCK_NODES) ? scn[tid - s] : 0;
        __syncthreads();
        if (tid < BUCK_NODES) scn[tid] += add;
        __syncthreads();
    }
    int start = 0;
    if (tid < BUCK_NODES) {
        start = e0 + scn[tid] - pad;
        cur[tid] = start;
        int node = blockIdx.x * BUCK_NODES + tid;
        if (node < n) {
            rowinfo[node] = make_int2(start, pad);
            dinv[node] = rsqrtf(1.0f + (float)v);
        }
    }
    __syncthreads();
    for (int e = e0 + tid; e < e1; e += 512) {
        unsigned p = packed[e];
        int pos = atomicAdd(&cur[p >> 17], 1);   // LDS cursor
        csr[pos] = (int)(p & 0x1FFFFu);          // dense slab window, L2-hot
    }
    __syncthreads();
    // append self edge, then dummy-pad (index n = zero bf16 row)
    if (tid < BUCK_NODES) {
        int node = blockIdx.x * BUCK_NODES + tid;
        csr[start + v] = (node < n) ? node : n;
        for (int p = v + 1; p < pad; ++p) csr[start + p] = n;
    }
}

// ---- GEMM (fp32 A): gBf[i][f] = bf16((A[i]@W)[f] * dinv[i]) ------------
// A-row pointer via readfirstlane -> SGPR -> scalar s_loads, v_fmac v,s,v.
__global__ __launch_bounds__(256) void k_gemm64bf(const float* __restrict__ A,
                                                  const float* __restrict__ W,
                                                  const float* __restrict__ dinv,
                                                  unsigned short* __restrict__ out,
                                                  int n) {
    const int lane = threadIdx.x & 63;
    const int wave = threadIdx.x >> 6;
    float wcol[64];
#pragma unroll
    for (int k = 0; k < 64; ++k) wcol[k] = W[k * 64 + lane];
    int base = blockIdx.x * 64;
    for (int r = wave; r < 64; r += 4) {
        int row = base + r;
        if (row >= n) break;
        int urow = __builtin_amdgcn_readfirstlane(row);   // SGPR row index
        const float* Ar = A + (size_t)urow * 64;          // uniform -> s_load path
        float acc = 0.0f;
#pragma unroll
        for (int k = 0; k < 64; ++k) acc = fmaf(Ar[k], wcol[k], acc);
        out[(size_t)urow * 64 + lane] = (unsigned short)rne_bf16(acc * dinv[urow]);
    }
}

// ---- GEMM (bf16 A): same, input rows are bf16 (h1) ---------------------
// Row dwords land in SGPRs; u<<16 / u&0xFFFF0000 are SALU (co-issue) ->
// still 1 VALU per FMA.
__global__ __launch_bounds__(256) void k_gemm64bf_h(const unsigned* __restrict__ A,
                                                    const float* __restrict__ W,
                                                    const float* __restrict__ dinv,
                                                    unsigned short* __restrict__ out,
                                                    int n) {
    const int lane = threadIdx.x & 63;
    const int wave = threadIdx.x >> 6;
    float wcol[64];
#pragma unroll
    for (int k = 0; k < 64; ++k) wcol[k] = W[k * 64 + lane];
    int base = blockIdx.x * 64;
    for (int r = wave; r < 64; r += 4) {
        int row = base + r;
        if (row >= n) break;
        int urow = __builtin_amdgcn_readfirstlane(row);   // SGPR row index
        const unsigned* Ar = A + (size_t)urow * 32;       // 32 dwords = 64 bf16
        float acc = 0.0f;
#pragma unroll
        for (int k = 0; k < 32; ++k) {
            unsigned u = Ar[k];                           // SGPR
            acc = fmaf(__uint_as_float(u << 16), wcol[2 * k], acc);
            acc = fmaf(__uint_as_float(u & 0xFFFF0000u), wcol[2 * k + 1], acc);
        }
        out[(size_t)urow * 64 + lane] = (unsigned short)rne_bf16(acc * dinv[urow]);
    }
}

__device__ __forceinline__ v2f bf2(unsigned u) {
    v2f r;
    r.x = __uint_as_float(u << 16);
    r.y = __uint_as_float(u & 0xFFFF0000u);
    return r;
}

// ---- Aggregate: FOUR nodes per wave (16 lanes each); bf16 rows ---------
// lane = 16*s + 8*grp + q; 4-deep gather unroll; self-loop in csr.
// Reduce: 1 halving round (mask 8). Epilogue: HALF=bf16 uint2 store (h1),
// else LAST=head GEMV.
template <bool LAST>
__global__ __launch_bounds__(256) void k_aggregate(
    const uint4* __restrict__ g4,
    const int2* __restrict__ rowinfo, const int* __restrict__ csr,
    const float* __restrict__ dinv, const float* __restrict__ bias,
    const float* __restrict__ Wo, const float* __restrict__ bo,
    unsigned* __restrict__ outRowBf, float* __restrict__ outHead, int n) {
    int w = (blockIdx.x * blockDim.x + threadIdx.x) >> 6;
    int lane = threadIdx.x & 63;
    const int s = lane >> 4;                  // node slot 0..3
    const int grp = (lane >> 3) & 1;          // 0..1
    const int q = lane & 7;                   // 0..7
    int node = 4 * w + s;
    const bool valid = node < n;
    int2 ri = valid ? rowinfo[node] : make_int2(0, 0);
    const int e = ri.x;
    const int rnds = ri.y >> 1;
    int rm = rnds;
    rm = max(rm, __shfl_xor(rm, 16, 64));
    rm = max(rm, __shfl_xor(rm, 32, 64));     // max over 4 slots
    v2f a0v = {0.f, 0.f}, a1v = {0.f, 0.f}, a2v = {0.f, 0.f}, a3v = {0.f, 0.f};
    int r = 0;
    for (; r + 4 <= rm; r += 4) {             // 32 edge-rows in flight / wave
        int c0 = csr[e + 2 * r + grp];        // shared base + imm offsets
        int c1 = csr[e + 2 * r + 2 + grp];
        int c2 = csr[e + 2 * r + 4 + grp];
        int c3 = csr[e + 2 * r + 6 + grp];
        int i0 = (r < rnds) ? c0 : n;
        int i1 = (r + 1 < rnds) ? c1 : n;
        int i2 = (r + 2 < rnds) ? c2 : n;
        int i3 = (r + 3 < rnds) ? c3 : n;
        uint4 x0 = g4[(size_t)i0 * 8 + q];
        uint4 x1 = g4[(size_t)i1 * 8 + q];
        uint4 x2 = g4[(size_t)i2 * 8 + q];
        uint4 x3 = g4[(size_t)i3 * 8 + q];
        a0v += bf2(x0.x); a1v += bf2(x0.y); a2v += bf2(x0.z); a3v += bf2(x0.w);
        a0v += bf2(x1.x); a1v += bf2(x1.y); a2v += bf2(x1.z); a3v += bf2(x1.w);
        a0v += bf2(x2.x); a1v += bf2(x2.y); a2v += bf2(x2.z); a3v += bf2(x2.w);
        a0v += bf2(x3.x); a1v += bf2(x3.y); a2v += bf2(x3.z); a3v += bf2(x3.w);
    }
    for (; r < rm; ++r) {                     // tail (<=3 rounds)
        int c0 = csr[e + 2 * r + grp];
        int i0 = (r < rnds) ? c0 : n;
        uint4 x0 = g4[(size_t)i0 * 8 + q];
        a0v += bf2(x0.x); a1v += bf2(x0.y); a2v += bf2(x0.z); a3v += bf2(x0.w);
    }
    // one halving round over grp (mask 8): grp0 ends with feat 8q..8q+3,
    // grp1 with 8q+4..8q+7
    v2f keep0 = grp ? a2v : a0v;
    v2f keep1 = grp ? a3v : a1v;
    v2f send0 = grp ? a0v : a2v;
    v2f send1 = grp ? a1v : a3v;
    keep0.x += __shfl_xor(send0.x, 8, 64);
    keep0.y += __shfl_xor(send0.y, 8, 64);
    keep1.x += __shfl_xor(send1.x, 8, 64);
    keep1.y += __shfl_xor(send1.y, 8, 64);
    const int base = 8 * q + 4 * grp;
    float dv = valid ? dinv[node] : 0.f;
    float4 bb = *(const float4*)&bias[base];
    float4 vv;
    vv.x = fmaxf(fmaf(dv, keep0.x, bb.x), 0.f);
    vv.y = fmaxf(fmaf(dv, keep0.y, bb.y), 0.f);
    vv.z = fmaxf(fmaf(dv, keep1.x, bb.z), 0.f);
    vv.w = fmaxf(fmaf(dv, keep1.y, bb.w), 0.f);
    if constexpr (LAST) {
        float4 ww = *(const float4*)&Wo[base];
        float p = vv.x * ww.x + vv.y * ww.y + vv.z * ww.z + vv.w * ww.w;
#pragma unroll
        for (int m = 1; m <= 8; m <<= 1) p += __shfl_xor(p, m, 64);
        if ((lane & 15) == 0 && valid) outHead[node] = p + bo[0];
    } else {
        if (valid) {
            uint2 o;
            o.x = rne_bf16(vv.x) | (rne_bf16(vv.y) << 16);
            o.y = rne_bf16(vv.z) | (rne_bf16(vv.w) << 16);
            *(uint2*)&outRowBf[(size_t)node * 32 + base / 2] = o;
        }
    }
}

extern "C" void kernel_launch(void* const* d_in, const int* in_sizes, int n_in,
                              void* d_out, int out_size, void* d_ws, size_t ws_size,
                              hipStream_t stream) {
    const float* x  = (const float*)d_in[0];
    const int*   ei = (const int*)d_in[1];
    const float* W1 = (const float*)d_in[2];
    const float* b1 = (const float*)d_in[3];
    const float* W2 = (const float*)d_in[4];
    const float* b2 = (const float*)d_in[5];
    const float* Wo = (const float*)d_in[6];
    const float* bo = (const float*)d_in[7];
    float* out = (float*)d_out;

    const int n = in_sizes[0] / 64;
    const int E = in_sizes[1] / 2;
    const int* src = ei;
    const int* dst = ei + E;

    const int nbuck = (n + BUCK_NODES - 1) >> NB_SHIFT;      // 391
    const int nchunks = (E + CHUNK - 1) / CHUNK;             // 306

    char* ws = (char*)d_ws;
    size_t off = 0;
    auto alloc = [&](size_t bytes) -> void* {
        void* p = ws + off;
        off += (bytes + 255) & ~(size_t)255;
        return p;
    };
    const size_t slabBytes = (size_t)nbuck * CAP * 4 + 4096; // 8.0 MB (+over-read slack)
    const size_t gBytes    = (size_t)(n + 1) * 64 * 2;       // 12.8 MB (bf16 g + dummy)
    const size_t hBytes    = (size_t)n * 64 * 2;             // 12.8 MB (bf16 h1)
    float*          dinv    = (float*)alloc((size_t)n * 4);
    int*            gcur    = (int*)alloc((size_t)nbuck * 4);
    int2*           rowinfo = (int2*)alloc((size_t)n * 8);
    int*            csr     = (int*)alloc(slabBytes);
    char*           regionA = (char*)alloc(hBytes > slabBytes ? hBytes : slabBytes);
    unsigned short* gBf     = (unsigned short*)alloc(gBytes);
    unsigned* packed = (unsigned*)regionA;   // dead after k_csr
    unsigned* bufH   = (unsigned*)regionA;   // h1 (bf16), written from agg1 on

    // ---- init (slab cursors + dummy bf16 row) ----
    k_init<<<1, 512, 0, stream>>>(gcur, nbuck, gBf + (size_t)n * 64);

    // ---- slab counting sort -> dst-sorted csr slabs + rowinfo + dinv ----
    k_bsort<<<nchunks, STPB, 0, stream>>>(src, dst, E, nbuck, gcur, packed);
    k_csr<<<nbuck, 512, 0, stream>>>(packed, gcur, n, csr, rowinfo, dinv);

    const int gemmGrid = (n + 63) / 64;
    const int nodeGrid = (n + 15) / 16;      // 4 nodes/wave, 4 waves/block

    // ---- layer 1 ----
    k_gemm64bf<<<gemmGrid, 256, 0, stream>>>(x, W1, dinv, gBf, n);
    k_aggregate<false><<<nodeGrid, 256, 0, stream>>>((const uint4*)gBf, rowinfo, csr,
                                                     dinv, b1, nullptr, nullptr,
                                                     bufH, nullptr, n);
    // ---- layer 2 (bf16 h1 input; head fused into epilogue) ----
    k_gemm64bf_h<<<gemmGrid, 256, 0, stream>>>(bufH, W2, dinv, gBf, n);
    k_aggregate<true><<<nodeGrid, 256, 0, stream>>>((const uint4*)gBf, rowinfo, csr,
                                                    dinv, b2, Wo, bo,
                                                    nullptr, out, n);
}

// Round 19
// 135.377 us; speedup vs baseline: 1.0255x; 1.0223x over previous
//
#include <hip/hip_runtime.h>

// GCN 2-layer + linear head on MI355X.
// R18 post-mortem: bf16 h1 regressed (+2.2 vs R16) -- per-wave issue is 1
// instr/cy, so SALU unpack doubles gemm2's instruction stream; fetch wasn't
// the binding constraint. Reverted to fp32 h1 (R16 state).
// R19: sort-chain barrier reduction -- Hillis-Steele scans (18/16 barriers)
// replaced by 2-barrier wave-shfl scans; k_bsort register-caches dst between
// passes. agg/gemm byte-identical to R16.

typedef float v2f __attribute__((ext_vector_type(2)));

constexpr int NB_SHIFT = 8;                 // 256 nodes per bucket
constexpr int BUCK_NODES = 1 << NB_SHIFT;
constexpr int CAP = 5120;                   // slab cap (max bucket ~3500 + 512 self + pad)
constexpr int CHUNK = 4096;                 // edges per sort block
constexpr int STPB = 512;
// assumes nbuck <= 512, src < 2^17, padded bucket size <= CAP

// ---- init: slab cursors + dummy bf16 row (replaces hipMemsetAsync) -----
__global__ __launch_bounds__(512) void k_init(int* __restrict__ gcur, int nbuck,
                                              unsigned short* __restrict__ dummyRow) {
    int t = threadIdx.x;
    if (t < nbuck) gcur[t] = 0;
    if (t < 64) dummyRow[t] = 0;
}

// inclusive block scan (512 threads) via wave shfl + 8-entry LDS; 2 barriers
__device__ __forceinline__ int blockScanIncl(int v, int tid, int* wsum) {
    int lane = tid & 63, wv = tid >> 6;
    int inc = v;
#pragma unroll
    for (int s = 1; s < 64; s <<= 1) {
        int t = __shfl_up(inc, s, 64);
        if (lane >= s) inc += t;
    }
    if (lane == 63) wsum[wv] = inc;
    __syncthreads();
    if (wv == 0 && lane < 8) {
        int t = wsum[lane];
#pragma unroll
        for (int s = 1; s < 8; s <<= 1) {
            int u = __shfl_up(t, s, 64);
            if (lane >= s) t += u;
        }
        wsum[lane] = t;
    }
    __syncthreads();
    return (wv > 0) ? inc + wsum[wv - 1] : inc;
}

// ---- fused: chunk histogram -> slab reserve -> LDS sort -> dense flush -
__global__ __launch_bounds__(STPB) void k_bsort(const int* __restrict__ src,
                                                const int* __restrict__ dst, int E, int nbuck,
                                                int* __restrict__ gcur,
                                                unsigned* __restrict__ packed) {
    __shared__ int shStart[512];
    __shared__ int shCur[512];
    __shared__ int shOff[512];
    __shared__ int wsum[8];
    __shared__ unsigned stage[CHUNK];
    __shared__ unsigned short sbkt[CHUNK];
    const int tid = threadIdx.x;
    const int base = blockIdx.x * CHUNK;
    const int end = min(base + CHUNK, E);
    // pass A: count buckets in this chunk (LDS atomics); cache dst in regs
    int myD[CHUNK / STPB];
    shCur[tid] = 0;
    __syncthreads();
    {
        int j = 0;
        for (int e = base + tid; e < end; e += STPB, ++j) {
            int d = dst[e];
            myD[j] = d;
            atomicAdd(&shCur[d >> NB_SHIFT], 1);
        }
    }
    __syncthreads();
    int v = shCur[tid];
    int inc = blockScanIncl(v, tid, wsum);    // 2 barriers (was 18)
    int exc = inc - v;
    shStart[tid] = exc;
    shCur[tid] = exc;
    // reserve this chunk's span in bucket slabs (one global atomic each)
    if (tid < nbuck) shOff[tid] = tid * CAP + ((v > 0) ? atomicAdd(&gcur[tid], v) : 0);
    __syncthreads();
    // pass B: permute chunk into LDS, bucket-major (dst from registers)
    {
        int j = 0;
        for (int e = base + tid; e < end; e += STPB, ++j) {
            int s = src[e];
            int d = myD[j];
            int b = d >> NB_SHIFT;
            int slot = atomicAdd(&shCur[b], 1);
            stage[slot] = ((unsigned)(d & (BUCK_NODES - 1)) << 17) | (unsigned)s;
            sbkt[slot] = (unsigned short)b;
        }
    }
    __syncthreads();
    // pass C: linear flush, same-bucket runs land contiguously
    int cnt = end - base;
    for (int i = tid; i < cnt; i += STPB) {
        int b = sbkt[i];
        packed[shOff[b] + (i - shStart[b])] = stage[i];
    }
}

// ---- per-bucket counting sort by dstLocal -> csr slab; appends SELF edge
//      then pads to x2. rowinfo=(start, paddedCount), dinv ---------------
__global__ __launch_bounds__(512) void k_csr(const unsigned* __restrict__ packed,
                                             const int* __restrict__ gcur, int n,
                                             int* __restrict__ csr, int2* __restrict__ rowinfo,
                                             float* __restrict__ dinv) {
    __shared__ int cnt[BUCK_NODES];
    __shared__ int cur[BUCK_NODES];
    __shared__ int wsum[8];
    const int tid = threadIdx.x;
    const int e0 = blockIdx.x * CAP;
    const int e1 = e0 + gcur[blockIdx.x];     // slab base + size
    if (tid < BUCK_NODES) cnt[tid] = 0;
    __syncthreads();
    for (int e = e0 + tid; e < e1; e += 512)
        atomicAdd(&cnt[packed[e] >> 17], 1);
    __syncthreads();
    int v = (tid < BUCK_NODES) ? cnt[tid] : 0;
    int pad = (tid < BUCK_NODES) ? ((v + 2) & ~1) : 0;   // v + self, round x2
    int inc = blockScanIncl(pad, tid, wsum);  // 2 barriers (was 16)
    int start = 0;
    if (tid < BUCK_NODES) {
        start = e0 + inc - pad;
        cur[tid] = start;
        int node = blockIdx.x * BUCK_NODES + tid;
        if (node < n) {
            rowinfo[node] = make_int2(start, pad);
            dinv[node] = rsqrtf(1.0f + (float)v);
        }
    }
    __syncthreads();
    for (int e = e0 + tid; e < e1; e += 512) {
        unsigned p = packed[e];
        int pos = atomicAdd(&cur[p >> 17], 1);   // LDS cursor
        csr[pos] = (int)(p & 0x1FFFFu);          // dense slab window, L2-hot
    }
    __syncthreads();
    // append self edge, then dummy-pad (index n = zero bf16 row)
    if (tid < BUCK_NODES) {
        int node = blockIdx.x * BUCK_NODES + tid;
        csr[start + v] = (node < n) ? node : n;
        for (int p = v + 1; p < pad; ++p) csr[start + p] = n;
    }
}

// ---- GEMM: gBf[i][f] = bf16((sum_k A[i][k] * W[k][f]) * dinv[i]) -------
// A-row pointer forced to SGPR via readfirstlane -> scalar s_loads,
// v_fmac v,s,v = 1 VALU instr per FMA. (Timed-graph verified: R13/R14/R15.)
__global__ __launch_bounds__(256) void k_gemm64bf(const float* __restrict__ A,
                                                  const float* __restrict__ W,
                                                  const float* __restrict__ dinv,
                                                  unsigned short* __restrict__ out,
                                                  int n) {
    const int lane = threadIdx.x & 63;
    const int wave = threadIdx.x >> 6;
    float wcol[64];
#pragma unroll
    for (int k = 0; k < 64; ++k) wcol[k] = W[k * 64 + lane];
    int base = blockIdx.x * 64;
    for (int r = wave; r < 64; r += 4) {
        int row = base + r;
        if (row >= n) break;
        int urow = __builtin_amdgcn_readfirstlane(row);   // SGPR row index
        const float* Ar = A + (size_t)urow * 64;          // uniform -> s_load path
        float acc = 0.0f;
#pragma unroll
        for (int k = 0; k < 64; ++k) acc = fmaf(Ar[k], wcol[k], acc);
        float val = acc * dinv[urow];
        unsigned u = __float_as_uint(val);
        u = (u + 0x7FFFu + ((u >> 16) & 1u)) >> 16;   // RNE to bf16
        out[(size_t)urow * 64 + lane] = (unsigned short)u;
    }
}

__device__ __forceinline__ v2f bf2(unsigned u) {
    v2f r;
    r.x = __uint_as_float(u << 16);
    r.y = __uint_as_float(u & 0xFFFF0000u);
    return r;
}

// ---- Aggregate: FOUR nodes per wave (16 lanes each); bf16 rows ---------
// lane = 16*s + 8*grp + q; 4-deep gather unroll; self-loop in csr.
// Reduce: 1 halving round (mask 8); float4 epilogue (fp32 h1) or head GEMV.
template <bool LAST>
__global__ __launch_bounds__(256) void k_aggregate(
    const uint4* __restrict__ g4,
    const int2* __restrict__ rowinfo, const int* __restrict__ csr,
    const float* __restrict__ dinv, const float* __restrict__ bias,
    const float* __restrict__ Wo, const float* __restrict__ bo,
    float* __restrict__ outRow, float* __restrict__ outHead, int n) {
    int w = (blockIdx.x * blockDim.x + threadIdx.x) >> 6;
    int lane = threadIdx.x & 63;
    const int s = lane >> 4;                  // node slot 0..3
    const int grp = (lane >> 3) & 1;          // 0..1
    const int q = lane & 7;                   // 0..7
    int node = 4 * w + s;
    const bool valid = node < n;
    int2 ri = valid ? rowinfo[node] : make_int2(0, 0);
    const int e = ri.x;
    const int rnds = ri.y >> 1;
    int rm = rnds;
    rm = max(rm, __shfl_xor(rm, 16, 64));
    rm = max(rm, __shfl_xor(rm, 32, 64));     // max over 4 slots
    v2f a0v = {0.f, 0.f}, a1v = {0.f, 0.f}, a2v = {0.f, 0.f}, a3v = {0.f, 0.f};
    int r = 0;
    for (; r + 4 <= rm; r += 4) {             // 32 edge-rows in flight / wave
        int c0 = csr[e + 2 * r + grp];        // shared base + imm offsets
        int c1 = csr[e + 2 * r + 2 + grp];
        int c2 = csr[e + 2 * r + 4 + grp];
        int c3 = csr[e + 2 * r + 6 + grp];
        int i0 = (r < rnds) ? c0 : n;
        int i1 = (r + 1 < rnds) ? c1 : n;
        int i2 = (r + 2 < rnds) ? c2 : n;
        int i3 = (r + 3 < rnds) ? c3 : n;
        uint4 x0 = g4[(size_t)i0 * 8 + q];
        uint4 x1 = g4[(size_t)i1 * 8 + q];
        uint4 x2 = g4[(size_t)i2 * 8 + q];
        uint4 x3 = g4[(size_t)i3 * 8 + q];
        a0v += bf2(x0.x); a1v += bf2(x0.y); a2v += bf2(x0.z); a3v += bf2(x0.w);
        a0v += bf2(x1.x); a1v += bf2(x1.y); a2v += bf2(x1.z); a3v += bf2(x1.w);
        a0v += bf2(x2.x); a1v += bf2(x2.y); a2v += bf2(x2.z); a3v += bf2(x2.w);
        a0v += bf2(x3.x); a1v += bf2(x3.y); a2v += bf2(x3.z); a3v += bf2(x3.w);
    }
    for (; r < rm; ++r) {                     // tail (<=3 rounds)
        int c0 = csr[e + 2 * r + grp];
        int i0 = (r < rnds) ? c0 : n;
        uint4 x0 = g4[(size_t)i0 * 8 + q];
        a0v += bf2(x0.x); a1v += bf2(x0.y); a2v += bf2(x0.z); a3v += bf2(x0.w);
    }
    // one halving round over grp (mask 8): grp0 ends with feat 8q..8q+3,
    // grp1 with 8q+4..8q+7
    v2f keep0 = grp ? a2v : a0v;
    v2f keep1 = grp ? a3v : a1v;
    v2f send0 = grp ? a0v : a2v;
    v2f send1 = grp ? a1v : a3v;
    keep0.x += __shfl_xor(send0.x, 8, 64);
    keep0.y += __shfl_xor(send0.y, 8, 64);
    keep1.x += __shfl_xor(send1.x, 8, 64);
    keep1.y += __shfl_xor(send1.y, 8, 64);
    const int base = 8 * q + 4 * grp;
    float dv = valid ? dinv[node] : 0.f;
    float4 bb = *(const float4*)&bias[base];
    float4 vv;
    vv.x = fmaxf(fmaf(dv, keep0.x, bb.x), 0.f);
    vv.y = fmaxf(fmaf(dv, keep0.y, bb.y), 0.f);
    vv.z = fmaxf(fmaf(dv, keep1.x, bb.z), 0.f);
    vv.w = fmaxf(fmaf(dv, keep1.y, bb.w), 0.f);
    if constexpr (LAST) {
        float4 ww = *(const float4*)&Wo[base];
        float p = vv.x * ww.x + vv.y * ww.y + vv.z * ww.z + vv.w * ww.w;
#pragma unroll
        for (int m = 1; m <= 8; m <<= 1) p += __shfl_xor(p, m, 64);
        if ((lane & 15) == 0 && valid) outHead[node] = p + bo[0];
    } else {
        if (valid) *(float4*)&outRow[(size_t)node * 64 + base] = vv;
    }
}

extern "C" void kernel_launch(void* const* d_in, const int* in_sizes, int n_in,
                              void* d_out, int out_size, void* d_ws, size_t ws_size,
                              hipStream_t stream) {
    const float* x  = (const float*)d_in[0];
    const int*   ei = (const int*)d_in[1];
    const float* W1 = (const float*)d_in[2];
    const float* b1 = (const float*)d_in[3];
    const float* W2 = (const float*)d_in[4];
    const float* b2 = (const float*)d_in[5];
    const float* Wo = (const float*)d_in[6];
    const float* bo = (const float*)d_in[7];
    float* out = (float*)d_out;

    const int n = in_sizes[0] / 64;
    const int E = in_sizes[1] / 2;
    const int* src = ei;
    const int* dst = ei + E;

    const int nbuck = (n + BUCK_NODES - 1) >> NB_SHIFT;      // 391
    const int nchunks = (E + CHUNK - 1) / CHUNK;             // 306

    char* ws = (char*)d_ws;
    size_t off = 0;
    auto alloc = [&](size_t bytes) -> void* {
        void* p = ws + off;
        off += (bytes + 255) & ~(size_t)255;
        return p;
    };
    const size_t slabBytes = (size_t)nbuck * CAP * 4 + 4096; // 8.0 MB (+over-read slack)
    const size_t hBytes    = (size_t)n * 64 * 4;             // 25.6 MB (fp32 h1)
    const size_t gBytes    = (size_t)(n + 1) * 64 * 2;       // 12.8 MB (bf16 g + dummy)
    float*          dinv    = (float*)alloc((size_t)n * 4);
    int*            gcur    = (int*)alloc((size_t)nbuck * 4);
    int2*           rowinfo = (int2*)alloc((size_t)n * 8);
    int*            csr     = (int*)alloc(slabBytes);
    char*           regionA = (char*)alloc(hBytes > slabBytes ? hBytes : slabBytes);
    unsigned short* gBf     = (unsigned short*)alloc(gBytes);
    unsigned* packed = (unsigned*)regionA;   // dead after k_csr
    float*    bufH   = (float*)regionA;      // h1 (fp32), written from agg1 on

    // ---- init (slab cursors + dummy bf16 row) ----
    k_init<<<1, 512, 0, stream>>>(gcur, nbuck, gBf + (size_t)n * 64);

    // ---- slab counting sort -> dst-sorted csr slabs + rowinfo + dinv ----
    k_bsort<<<nchunks, STPB, 0, stream>>>(src, dst, E, nbuck, gcur, packed);
    k_csr<<<nbuck, 512, 0, stream>>>(packed, gcur, n, csr, rowinfo, dinv);

    const int gemmGrid = (n + 63) / 64;
    const int nodeGrid = (n + 15) / 16;      // 4 nodes/wave, 4 waves/block

    // ---- layer 1 ----
    k_gemm64bf<<<gemmGrid, 256, 0, stream>>>(x, W1, dinv, gBf, n);
    k_aggregate<false><<<nodeGrid, 256, 0, stream>>>((const uint4*)gBf, rowinfo, csr,
                                                     dinv, b1, nullptr, nullptr,
                                                     bufH, nullptr, n);
    // ---- layer 2 (head fused into epilogue) ----
    k_gemm64bf<<<gemmGrid, 256, 0, stream>>>(bufH, W2, dinv, gBf, n);
    k_aggregate<true><<<nodeGrid, 256, 0, stream>>>((const uint4*)gBf, rowinfo, csr,
                                                    dinv, b2, Wo, bo,
                                                    nullptr, out, n);
}

// Round 20
// 135.189 us; speedup vs baseline: 1.0270x; 1.0014x over previous
//
#include <hip/hip_runtime.h>

// GCN 2-layer + linear head on MI355X.
// R19 post-mortem: scan-barrier fix neutral (135.4). Key clue: k_gemm64bf
// VGPR_Count=36 < the 64 needed for wcol residency -> compiler re-loads W
// inside the row loop (doubles issue stream; FETCH == A bytes exactly).
// R20: __launch_bounds__(256,1) on the GEMM only -- lets the allocator keep
// wcol in VGPRs (~104, still ~4 waves/SIMD). Everything else == R19.

typedef float v2f __attribute__((ext_vector_type(2)));

constexpr int NB_SHIFT = 8;                 // 256 nodes per bucket
constexpr int BUCK_NODES = 1 << NB_SHIFT;
constexpr int CAP = 5120;                   // slab cap (max bucket ~3500 + 512 self + pad)
constexpr int CHUNK = 4096;                 // edges per sort block
constexpr int STPB = 512;
// assumes nbuck <= 512, src < 2^17, padded bucket size <= CAP

// ---- init: slab cursors + dummy bf16 row (replaces hipMemsetAsync) -----
__global__ __launch_bounds__(512) void k_init(int* __restrict__ gcur, int nbuck,
                                              unsigned short* __restrict__ dummyRow) {
    int t = threadIdx.x;
    if (t < nbuck) gcur[t] = 0;
    if (t < 64) dummyRow[t] = 0;
}

// inclusive block scan (512 threads) via wave shfl + 8-entry LDS; 2 barriers
__device__ __forceinline__ int blockScanIncl(int v, int tid, int* wsum) {
    int lane = tid & 63, wv = tid >> 6;
    int inc = v;
#pragma unroll
    for (int s = 1; s < 64; s <<= 1) {
        int t = __shfl_up(inc, s, 64);
        if (lane >= s) inc += t;
    }
    if (lane == 63) wsum[wv] = inc;
    __syncthreads();
    if (wv == 0 && lane < 8) {
        int t = wsum[lane];
#pragma unroll
        for (int s = 1; s < 8; s <<= 1) {
            int u = __shfl_up(t, s, 64);
            if (lane >= s) t += u;
        }
        wsum[lane] = t;
    }
    __syncthreads();
    return (wv > 0) ? inc + wsum[wv - 1] : inc;
}

// ---- fused: chunk histogram -> slab reserve -> LDS sort -> dense flush -
__global__ __launch_bounds__(STPB) void k_bsort(const int* __restrict__ src,
                                                const int* __restrict__ dst, int E, int nbuck,
                                                int* __restrict__ gcur,
                                                unsigned* __restrict__ packed) {
    __shared__ int shStart[512];
    __shared__ int shCur[512];
    __shared__ int shOff[512];
    __shared__ int wsum[8];
    __shared__ unsigned stage[CHUNK];
    __shared__ unsigned short sbkt[CHUNK];
    const int tid = threadIdx.x;
    const int base = blockIdx.x * CHUNK;
    const int end = min(base + CHUNK, E);
    // pass A: count buckets in this chunk (LDS atomics); cache dst in regs
    int myD[CHUNK / STPB];
    shCur[tid] = 0;
    __syncthreads();
    {
        int j = 0;
        for (int e = base + tid; e < end; e += STPB, ++j) {
            int d = dst[e];
            myD[j] = d;
            atomicAdd(&shCur[d >> NB_SHIFT], 1);
        }
    }
    __syncthreads();
    int v = shCur[tid];
    int inc = blockScanIncl(v, tid, wsum);    // 2 barriers
    int exc = inc - v;
    shStart[tid] = exc;
    shCur[tid] = exc;
    // reserve this chunk's span in bucket slabs (one global atomic each)
    if (tid < nbuck) shOff[tid] = tid * CAP + ((v > 0) ? atomicAdd(&gcur[tid], v) : 0);
    __syncthreads();
    // pass B: permute chunk into LDS, bucket-major (dst from registers)
    {
        int j = 0;
        for (int e = base + tid; e < end; e += STPB, ++j) {
            int s = src[e];
            int d = myD[j];
            int b = d >> NB_SHIFT;
            int slot = atomicAdd(&shCur[b], 1);
            stage[slot] = ((unsigned)(d & (BUCK_NODES - 1)) << 17) | (unsigned)s;
            sbkt[slot] = (unsigned short)b;
        }
    }
    __syncthreads();
    // pass C: linear flush, same-bucket runs land contiguously
    int cnt = end - base;
    for (int i = tid; i < cnt; i += STPB) {
        int b = sbkt[i];
        packed[shOff[b] + (i - shStart[b])] = stage[i];
    }
}

// ---- per-bucket counting sort by dstLocal -> csr slab; appends SELF edge
//      then pads to x2. rowinfo=(start, paddedCount), dinv ---------------
__global__ __launch_bounds__(512) void k_csr(const unsigned* __restrict__ packed,
                                             const int* __restrict__ gcur, int n,
                                             int* __restrict__ csr, int2* __restrict__ rowinfo,
                                             float* __restrict__ dinv) {
    __shared__ int cnt[BUCK_NODES];
    __shared__ int cur[BUCK_NODES];
    __shared__ int wsum[8];
    const int tid = threadIdx.x;
    const int e0 = blockIdx.x * CAP;
    const int e1 = e0 + gcur[blockIdx.x];     // slab base + size
    if (tid < BUCK_NODES) cnt[tid] = 0;
    __syncthreads();
    for (int e = e0 + tid; e < e1; e += 512)
        atomicAdd(&cnt[packed[e] >> 17], 1);
    __syncthreads();
    int v = (tid < BUCK_NODES) ? cnt[tid] : 0;
    int pad = (tid < BUCK_NODES) ? ((v + 2) & ~1) : 0;   // v + self, round x2
    int inc = blockScanIncl(pad, tid, wsum);  // 2 barriers
    int start = 0;
    if (tid < BUCK_NODES) {
        start = e0 + inc - pad;
        cur[tid] = start;
        int node = blockIdx.x * BUCK_NODES + tid;
        if (node < n) {
            rowinfo[node] = make_int2(start, pad);
            dinv[node] = rsqrtf(1.0f + (float)v);
        }
    }
    __syncthreads();
    for (int e = e0 + tid; e < e1; e += 512) {
        unsigned p = packed[e];
        int pos = atomicAdd(&cur[p >> 17], 1);   // LDS cursor
        csr[pos] = (int)(p & 0x1FFFFu);          // dense slab window, L2-hot
    }
    __syncthreads();
    // append self edge, then dummy-pad (index n = zero bf16 row)
    if (tid < BUCK_NODES) {
        int node = blockIdx.x * BUCK_NODES + tid;
        csr[start + v] = (node < n) ? node : n;
        for (int p = v + 1; p < pad; ++p) csr[start + p] = n;
    }
}

// ---- GEMM: gBf[i][f] = bf16((sum_k A[i][k] * W[k][f]) * dinv[i]) -------
// A-row pointer via readfirstlane -> SGPR -> scalar s_loads, v_fmac v,s,v.
// __launch_bounds__(256,1): allow ~104 VGPR so wcol[64] stays register-
// resident (was VGPR_Count=36 -> compiler re-loaded W per row).
__global__ __launch_bounds__(256, 1) void k_gemm64bf(const float* __restrict__ A,
                                                     const float* __restrict__ W,
                                                     const float* __restrict__ dinv,
                                                     unsigned short* __restrict__ out,
                                                     int n) {
    const int lane = threadIdx.x & 63;
    const int wave = threadIdx.x >> 6;
    float wcol[64];
#pragma unroll
    for (int k = 0; k < 64; ++k) wcol[k] = W[k * 64 + lane];
    int base = blockIdx.x * 64;
    for (int r = wave; r < 64; r += 4) {
        int row = base + r;
        if (row >= n) break;
        int urow = __builtin_amdgcn_readfirstlane(row);   // SGPR row index
        const float* Ar = A + (size_t)urow * 64;          // uniform -> s_load path
        float acc = 0.0f;
#pragma unroll
        for (int k = 0; k < 64; ++k) acc = fmaf(Ar[k], wcol[k], acc);
        float val = acc * dinv[urow];
        unsigned u = __float_as_uint(val);
        u = (u + 0x7FFFu + ((u >> 16) & 1u)) >> 16;   // RNE to bf16
        out[(size_t)urow * 64 + lane] = (unsigned short)u;
    }
}

__device__ __forceinline__ v2f bf2(unsigned u) {
    v2f r;
    r.x = __uint_as_float(u << 16);
    r.y = __uint_as_float(u & 0xFFFF0000u);
    return r;
}

// ---- Aggregate: FOUR nodes per wave (16 lanes each); bf16 rows ---------
// lane = 16*s + 8*grp + q; 4-deep gather unroll; self-loop in csr.
// Reduce: 1 halving round (mask 8); float4 epilogue (fp32 h1) or head GEMV.
template <bool LAST>
__global__ __launch_bounds__(256) void k_aggregate(
    const uint4* __restrict__ g4,
    const int2* __restrict__ rowinfo, const int* __restrict__ csr,
    const float* __restrict__ dinv, const float* __restrict__ bias,
    const float* __restrict__ Wo, const float* __restrict__ bo,
    float* __restrict__ outRow, float* __restrict__ outHead, int n) {
    int w = (blockIdx.x * blockDim.x + threadIdx.x) >> 6;
    int lane = threadIdx.x & 63;
    const int s = lane >> 4;                  // node slot 0..3
    const int grp = (lane >> 3) & 1;          // 0..1
    const int q = lane & 7;                   // 0..7
    int node = 4 * w + s;
    const bool valid = node < n;
    int2 ri = valid ? rowinfo[node] : make_int2(0, 0);
    const int e = ri.x;
    const int rnds = ri.y >> 1;
    int rm = rnds;
    rm = max(rm, __shfl_xor(rm, 16, 64));
    rm = max(rm, __shfl_xor(rm, 32, 64));     // max over 4 slots
    v2f a0v = {0.f, 0.f}, a1v = {0.f, 0.f}, a2v = {0.f, 0.f}, a3v = {0.f, 0.f};
    int r = 0;
    for (; r + 4 <= rm; r += 4) {             // 32 edge-rows in flight / wave
        int c0 = csr[e + 2 * r + grp];        // shared base + imm offsets
        int c1 = csr[e + 2 * r + 2 + grp];
        int c2 = csr[e + 2 * r + 4 + grp];
        int c3 = csr[e + 2 * r + 6 + grp];
        int i0 = (r < rnds) ? c0 : n;
        int i1 = (r + 1 < rnds) ? c1 : n;
        int i2 = (r + 2 < rnds) ? c2 : n;
        int i3 = (r + 3 < rnds) ? c3 : n;
        uint4 x0 = g4[(size_t)i0 * 8 + q];
        uint4 x1 = g4[(size_t)i1 * 8 + q];
        uint4 x2 = g4[(size_t)i2 * 8 + q];
        uint4 x3 = g4[(size_t)i3 * 8 + q];
        a0v += bf2(x0.x); a1v += bf2(x0.y); a2v += bf2(x0.z); a3v += bf2(x0.w);
        a0v += bf2(x1.x); a1v += bf2(x1.y); a2v += bf2(x1.z); a3v += bf2(x1.w);
        a0v += bf2(x2.x); a1v += bf2(x2.y); a2v += bf2(x2.z); a3v += bf2(x2.w);
        a0v += bf2(x3.x); a1v += bf2(x3.y); a2v += bf2(x3.z); a3v += bf2(x3.w);
    }
    for (; r < rm; ++r) {                     // tail (<=3 rounds)
        int c0 = csr[e + 2 * r + grp];
        int i0 = (r < rnds) ? c0 : n;
        uint4 x0 = g4[(size_t)i0 * 8 + q];
        a0v += bf2(x0.x); a1v += bf2(x0.y); a2v += bf2(x0.z); a3v += bf2(x0.w);
    }
    // one halving round over grp (mask 8): grp0 ends with feat 8q..8q+3,
    // grp1 with 8q+4..8q+7
    v2f keep0 = grp ? a2v : a0v;
    v2f keep1 = grp ? a3v : a1v;
    v2f send0 = grp ? a0v : a2v;
    v2f send1 = grp ? a1v : a3v;
    keep0.x += __shfl_xor(send0.x, 8, 64);
    keep0.y += __shfl_xor(send0.y, 8, 64);
    keep1.x += __shfl_xor(send1.x, 8, 64);
    keep1.y += __shfl_xor(send1.y, 8, 64);
    const int base = 8 * q + 4 * grp;
    float dv = valid ? dinv[node] : 0.f;
    float4 bb = *(const float4*)&bias[base];
    float4 vv;
    vv.x = fmaxf(fmaf(dv, keep0.x, bb.x), 0.f);
    vv.y = fmaxf(fmaf(dv, keep0.y, bb.y), 0.f);
    vv.z = fmaxf(fmaf(dv, keep1.x, bb.z), 0.f);
    vv.w = fmaxf(fmaf(dv, keep1.y, bb.w), 0.f);
    if constexpr (LAST) {
        float4 ww = *(const float4*)&Wo[base];
        float p = vv.x * ww.x + vv.y * ww.y + vv.z * ww.z + vv.w * ww.w;
#pragma unroll
        for (int m = 1; m <= 8; m <<= 1) p += __shfl_xor(p, m, 64);
        if ((lane & 15) == 0 && valid) outHead[node] = p + bo[0];
    } else {
        if (valid) *(float4*)&outRow[(size_t)node * 64 + base] = vv;
    }
}

extern "C" void kernel_launch(void* const* d_in, const int* in_sizes, int n_in,
                              void* d_out, int out_size, void* d_ws, size_t ws_size,
                              hipStream_t stream) {
    const float* x  = (const float*)d_in[0];
    const int*   ei = (const int*)d_in[1];
    const float* W1 = (const float*)d_in[2];
    const float* b1 = (const float*)d_in[3];
    const float* W2 = (const float*)d_in[4];
    const float* b2 = (const float*)d_in[5];
    const float* Wo = (const float*)d_in[6];
    const float* bo = (const float*)d_in[7];
    float* out = (float*)d_out;

    const int n = in_sizes[0] / 64;
    const int E = in_sizes[1] / 2;
    const int* src = ei;
    const int* dst = ei + E;

    const int nbuck = (n + BUCK_NODES - 1) >> NB_SHIFT;      // 391
    const int nchunks = (E + CHUNK - 1) / CHUNK;             // 306

    char* ws = (char*)d_ws;
    size_t off = 0;
    auto alloc = [&](size_t bytes) -> void* {
        void* p = ws + off;
        off += (bytes + 255) & ~(size_t)255;
        return p;
    };
    const size_t slabBytes = (size_t)nbuck * CAP * 4 + 4096; // 8.0 MB (+over-read slack)
    const size_t hBytes    = (size_t)n * 64 * 4;             // 25.6 MB (fp32 h1)
    const size_t gBytes    = (size_t)(n + 1) * 64 * 2;       // 12.8 MB (bf16 g + dummy)
    float*          dinv    = (float*)alloc((size_t)n * 4);
    int*            gcur    = (int*)alloc((size_t)nbuck * 4);
    int2*           rowinfo = (int2*)alloc((size_t)n * 8);
    int*            csr     = (int*)alloc(slabBytes);
    char*           regionA = (char*)alloc(hBytes > slabBytes ? hBytes : slabBytes);
    unsigned short* gBf     = (unsigned short*)alloc(gBytes);
    unsigned* packed = (unsigned*)regionA;   // dead after k_csr
    float*    bufH   = (float*)regionA;      // h1 (fp32), written from agg1 on

    // ---- init (slab cursors + dummy bf16 row) ----
    k_init<<<1, 512, 0, stream>>>(gcur, nbuck, gBf + (size_t)n * 64);

    // ---- slab counting sort -> dst-sorted csr slabs + rowinfo + dinv ----
    k_bsort<<<nchunks, STPB, 0, stream>>>(src, dst, E, nbuck, gcur, packed);
    k_csr<<<nbuck, 512, 0, stream>>>(packed, gcur, n, csr, rowinfo, dinv);

    const int gemmGrid = (n + 63) / 64;
    const int nodeGrid = (n + 15) / 16;      // 4 nodes/wave, 4 waves/block

    // ---- layer 1 ----
    k_gemm64bf<<<gemmGrid, 256, 0, stream>>>(x, W1, dinv, gBf, n);
    k_aggregate<false><<<nodeGrid, 256, 0, stream>>>((const uint4*)gBf, rowinfo, csr,
                                                     dinv, b1, nullptr, nullptr,
                                                     bufH, nullptr, n);
    // ---- layer 2 (head fused into epilogue) ----
    k_gemm64bf<<<gemmGrid, 256, 0, stream>>>(bufH, W2, dinv, gBf, n);
    k_aggregate<true><<<nodeGrid, 256, 0, stream>>>((const uint4*)gBf, rowinfo, csr,
                                                    dinv, b2, Wo, bo,
                                                    nullptr, out, n);
}

// Round 21
// 134.970 us; speedup vs baseline: 1.0286x; 1.0016x over previous
//
#include <hip/hip_runtime.h>

// GCN 2-layer + linear head on MI355X.
// R20 post-mortem: launch_bounds(256,1) did NOT change VGPR_Count (36) --
// the allocator rematerializes wcol by heuristic, not pressure. R21: pin
// wcol[64] into VGPRs with opaque empty-asm ("+v") after the load; compiler
// can no longer re-load W inside the row loop -> 1 v_fmac per FMA.
// Everything else byte-identical to R20.

typedef float v2f __attribute__((ext_vector_type(2)));

constexpr int NB_SHIFT = 8;                 // 256 nodes per bucket
constexpr int BUCK_NODES = 1 << NB_SHIFT;
constexpr int CAP = 5120;                   // slab cap (max bucket ~3500 + 512 self + pad)
constexpr int CHUNK = 4096;                 // edges per sort block
constexpr int STPB = 512;
// assumes nbuck <= 512, src < 2^17, padded bucket size <= CAP

// ---- init: slab cursors + dummy bf16 row (replaces hipMemsetAsync) -----
__global__ __launch_bounds__(512) void k_init(int* __restrict__ gcur, int nbuck,
                                              unsigned short* __restrict__ dummyRow) {
    int t = threadIdx.x;
    if (t < nbuck) gcur[t] = 0;
    if (t < 64) dummyRow[t] = 0;
}

// inclusive block scan (512 threads) via wave shfl + 8-entry LDS; 2 barriers
__device__ __forceinline__ int blockScanIncl(int v, int tid, int* wsum) {
    int lane = tid & 63, wv = tid >> 6;
    int inc = v;
#pragma unroll
    for (int s = 1; s < 64; s <<= 1) {
        int t = __shfl_up(inc, s, 64);
        if (lane >= s) inc += t;
    }
    if (lane == 63) wsum[wv] = inc;
    __syncthreads();
    if (wv == 0 && lane < 8) {
        int t = wsum[lane];
#pragma unroll
        for (int s = 1; s < 8; s <<= 1) {
            int u = __shfl_up(t, s, 64);
            if (lane >= s) t += u;
        }
        wsum[lane] = t;
    }
    __syncthreads();
    return (wv > 0) ? inc + wsum[wv - 1] : inc;
}

// ---- fused: chunk histogram -> slab reserve -> LDS sort -> dense flush -
__global__ __launch_bounds__(STPB) void k_bsort(const int* __restrict__ src,
                                                const int* __restrict__ dst, int E, int nbuck,
                                                int* __restrict__ gcur,
                                                unsigned* __restrict__ packed) {
    __shared__ int shStart[512];
    __shared__ int shCur[512];
    __shared__ int shOff[512];
    __shared__ int wsum[8];
    __shared__ unsigned stage[CHUNK];
    __shared__ unsigned short sbkt[CHUNK];
    const int tid = threadIdx.x;
    const int base = blockIdx.x * CHUNK;
    const int end = min(base + CHUNK, E);
    // pass A: count buckets in this chunk (LDS atomics); cache dst in regs
    int myD[CHUNK / STPB];
    shCur[tid] = 0;
    __syncthreads();
    {
        int j = 0;
        for (int e = base + tid; e < end; e += STPB, ++j) {
            int d = dst[e];
            myD[j] = d;
            atomicAdd(&shCur[d >> NB_SHIFT], 1);
        }
    }
    __syncthreads();
    int v = shCur[tid];
    int inc = blockScanIncl(v, tid, wsum);    // 2 barriers
    int exc = inc - v;
    shStart[tid] = exc;
    shCur[tid] = exc;
    // reserve this chunk's span in bucket slabs (one global atomic each)
    if (tid < nbuck) shOff[tid] = tid * CAP + ((v > 0) ? atomicAdd(&gcur[tid], v) : 0);
    __syncthreads();
    // pass B: permute chunk into LDS, bucket-major (dst from registers)
    {
        int j = 0;
        for (int e = base + tid; e < end; e += STPB, ++j) {
            int s = src[e];
            int d = myD[j];
            int b = d >> NB_SHIFT;
            int slot = atomicAdd(&shCur[b], 1);
            stage[slot] = ((unsigned)(d & (BUCK_NODES - 1)) << 17) | (unsigned)s;
            sbkt[slot] = (unsigned short)b;
        }
    }
    __syncthreads();
    // pass C: linear flush, same-bucket runs land contiguously
    int cnt = end - base;
    for (int i = tid; i < cnt; i += STPB) {
        int b = sbkt[i];
        packed[shOff[b] + (i - shStart[b])] = stage[i];
    }
}

// ---- per-bucket counting sort by dstLocal -> csr slab; appends SELF edge
//      then pads to x2. rowinfo=(start, paddedCount), dinv ---------------
__global__ __launch_bounds__(512) void k_csr(const unsigned* __restrict__ packed,
                                             const int* __restrict__ gcur, int n,
                                             int* __restrict__ csr, int2* __restrict__ rowinfo,
                                             float* __restrict__ dinv) {
    __shared__ int cnt[BUCK_NODES];
    __shared__ int cur[BUCK_NODES];
    __shared__ int wsum[8];
    const int tid = threadIdx.x;
    const int e0 = blockIdx.x * CAP;
    const int e1 = e0 + gcur[blockIdx.x];     // slab base + size
    if (tid < BUCK_NODES) cnt[tid] = 0;
    __syncthreads();
    for (int e = e0 + tid; e < e1; e += 512)
        atomicAdd(&cnt[packed[e] >> 17], 1);
    __syncthreads();
    int v = (tid < BUCK_NODES) ? cnt[tid] : 0;
    int pad = (tid < BUCK_NODES) ? ((v + 2) & ~1) : 0;   // v + self, round x2
    int inc = blockScanIncl(pad, tid, wsum);  // 2 barriers
    int start = 0;
    if (tid < BUCK_NODES) {
        start = e0 + inc - pad;
        cur[tid] = start;
        int node = blockIdx.x * BUCK_NODES + tid;
        if (node < n) {
            rowinfo[node] = make_int2(start, pad);
            dinv[node] = rsqrtf(1.0f + (float)v);
        }
    }
    __syncthreads();
    for (int e = e0 + tid; e < e1; e += 512) {
        unsigned p = packed[e];
        int pos = atomicAdd(&cur[p >> 17], 1);   // LDS cursor
        csr[pos] = (int)(p & 0x1FFFFu);          // dense slab window, L2-hot
    }
    __syncthreads();
    // append self edge, then dummy-pad (index n = zero bf16 row)
    if (tid < BUCK_NODES) {
        int node = blockIdx.x * BUCK_NODES + tid;
        csr[start + v] = (node < n) ? node : n;
        for (int p = v + 1; p < pad; ++p) csr[start + p] = n;
    }
}

// ---- GEMM: gBf[i][f] = bf16((sum_k A[i][k] * W[k][f]) * dinv[i]) -------
// A-row pointer via readfirstlane -> SGPR -> scalar s_loads, v_fmac v,s,v.
// wcol pinned to VGPRs via opaque empty-asm (compiler cannot rematerialize).
__global__ __launch_bounds__(256, 1) void k_gemm64bf(const float* __restrict__ A,
                                                     const float* __restrict__ W,
                                                     const float* __restrict__ dinv,
                                                     unsigned short* __restrict__ out,
                                                     int n) {
    const int lane = threadIdx.x & 63;
    const int wave = threadIdx.x >> 6;
    float wcol[64];
#pragma unroll
    for (int k = 0; k < 64; ++k) wcol[k] = W[k * 64 + lane];
#pragma unroll
    for (int k = 0; k < 64; ++k) asm volatile("" : "+v"(wcol[k]));  // pin in VGPRs
    int base = blockIdx.x * 64;
    for (int r = wave; r < 64; r += 4) {
        int row = base + r;
        if (row >= n) break;
        int urow = __builtin_amdgcn_readfirstlane(row);   // SGPR row index
        const float* Ar = A + (size_t)urow * 64;          // uniform -> s_load path
        float acc = 0.0f;
#pragma unroll
        for (int k = 0; k < 64; ++k) acc = fmaf(Ar[k], wcol[k], acc);
        float val = acc * dinv[urow];
        unsigned u = __float_as_uint(val);
        u = (u + 0x7FFFu + ((u >> 16) & 1u)) >> 16;   // RNE to bf16
        out[(size_t)urow * 64 + lane] = (unsigned short)u;
    }
}

__device__ __forceinline__ v2f bf2(unsigned u) {
    v2f r;
    r.x = __uint_as_float(u << 16);
    r.y = __uint_as_float(u & 0xFFFF0000u);
    return r;
}

// ---- Aggregate: FOUR nodes per wave (16 lanes each); bf16 rows ---------
// lane = 16*s + 8*grp + q; 4-deep gather unroll; self-loop in csr.
// Reduce: 1 halving round (mask 8); float4 epilogue (fp32 h1) or head GEMV.
template <bool LAST>
__global__ __launch_bounds__(256) void k_aggregate(
    const uint4* __restrict__ g4,
    const int2* __restrict__ rowinfo, const int* __restrict__ csr,
    const float* __restrict__ dinv, const float* __restrict__ bias,
    const float* __restrict__ Wo, const float* __restrict__ bo,
    float* __restrict__ outRow, float* __restrict__ outHead, int n) {
    int w = (blockIdx.x * blockDim.x + threadIdx.x) >> 6;
    int lane = threadIdx.x & 63;
    const int s = lane >> 4;                  // node slot 0..3
    const int grp = (lane >> 3) & 1;          // 0..1
    const int q = lane & 7;                   // 0..7
    int node = 4 * w + s;
    const bool valid = node < n;
    int2 ri = valid ? rowinfo[node] : make_int2(0, 0);
    const int e = ri.x;
    const int rnds = ri.y >> 1;
    int rm = rnds;
    rm = max(rm, __shfl_xor(rm, 16, 64));
    rm = max(rm, __shfl_xor(rm, 32, 64));     // max over 4 slots
    v2f a0v = {0.f, 0.f}, a1v = {0.f, 0.f}, a2v = {0.f, 0.f}, a3v = {0.f, 0.f};
    int r = 0;
    for (; r + 4 <= rm; r += 4) {             // 32 edge-rows in flight / wave
        int c0 = csr[e + 2 * r + grp];        // shared base + imm offsets
        int c1 = csr[e + 2 * r + 2 + grp];
        int c2 = csr[e + 2 * r + 4 + grp];
        int c3 = csr[e + 2 * r + 6 + grp];
        int i0 = (r < rnds) ? c0 : n;
        int i1 = (r + 1 < rnds) ? c1 : n;
        int i2 = (r + 2 < rnds) ? c2 : n;
        int i3 = (r + 3 < rnds) ? c3 : n;
        uint4 x0 = g4[(size_t)i0 * 8 + q];
        uint4 x1 = g4[(size_t)i1 * 8 + q];
        uint4 x2 = g4[(size_t)i2 * 8 + q];
        uint4 x3 = g4[(size_t)i3 * 8 + q];
        a0v += bf2(x0.x); a1v += bf2(x0.y); a2v += bf2(x0.z); a3v += bf2(x0.w);
        a0v += bf2(x1.x); a1v += bf2(x1.y); a2v += bf2(x1.z); a3v += bf2(x1.w);
        a0v += bf2(x2.x); a1v += bf2(x2.y); a2v += bf2(x2.z); a3v += bf2(x2.w);
        a0v += bf2(x3.x); a1v += bf2(x3.y); a2v += bf2(x3.z); a3v += bf2(x3.w);
    }
    for (; r < rm; ++r) {                     // tail (<=3 rounds)
        int c0 = csr[e + 2 * r + grp];
        int i0 = (r < rnds) ? c0 : n;
        uint4 x0 = g4[(size_t)i0 * 8 + q];
        a0v += bf2(x0.x); a1v += bf2(x0.y); a2v += bf2(x0.z); a3v += bf2(x0.w);
    }
    // one halving round over grp (mask 8): grp0 ends with feat 8q..8q+3,
    // grp1 with 8q+4..8q+7
    v2f keep0 = grp ? a2v : a0v;
    v2f keep1 = grp ? a3v : a1v;
    v2f send0 = grp ? a0v : a2v;
    v2f send1 = grp ? a1v : a3v;
    keep0.x += __shfl_xor(send0.x, 8, 64);
    keep0.y += __shfl_xor(send0.y, 8, 64);
    keep1.x += __shfl_xor(send1.x, 8, 64);
    keep1.y += __shfl_xor(send1.y, 8, 64);
    const int base = 8 * q + 4 * grp;
    float dv = valid ? dinv[node] : 0.f;
    float4 bb = *(const float4*)&bias[base];
    float4 vv;
    vv.x = fmaxf(fmaf(dv, keep0.x, bb.x), 0.f);
    vv.y = fmaxf(fmaf(dv, keep0.y, bb.y), 0.f);
    vv.z = fmaxf(fmaf(dv, keep1.x, bb.z), 0.f);
    vv.w = fmaxf(fmaf(dv, keep1.y, bb.w), 0.f);
    if constexpr (LAST) {
        float4 ww = *(const float4*)&Wo[base];
        float p = vv.x * ww.x + vv.y * ww.y + vv.z * ww.z + vv.w * ww.w;
#pragma unroll
        for (int m = 1; m <= 8; m <<= 1) p += __shfl_xor(p, m, 64);
        if ((lane & 15) == 0 && valid) outHead[node] = p + bo[0];
    } else {
        if (valid) *(float4*)&outRow[(size_t)node * 64 + base] = vv;
    }
}

extern "C" void kernel_launch(void* const* d_in, const int* in_sizes, int n_in,
                              void* d_out, int out_size, void* d_ws, size_t ws_size,
                              hipStream_t stream) {
    const float* x  = (const float*)d_in[0];
    const int*   ei = (const int*)d_in[1];
    const float* W1 = (const float*)d_in[2];
    const float* b1 = (const float*)d_in[3];
    const float* W2 = (const float*)d_in[4];
    const float* b2 = (const float*)d_in[5];
    const float* Wo = (const float*)d_in[6];
    const float* bo = (const float*)d_in[7];
    float* out = (float*)d_out;

    const int n = in_sizes[0] / 64;
    const int E = in_sizes[1] / 2;
    const int* src = ei;
    const int* dst = ei + E;

    const int nbuck = (n + BUCK_NODES - 1) >> NB_SHIFT;      // 391
    const int nchunks = (E + CHUNK - 1) / CHUNK;             // 306

    char* ws = (char*)d_ws;
    size_t off = 0;
    auto alloc = [&](size_t bytes) -> void* {
        void* p = ws + off;
        off += (bytes + 255) & ~(size_t)255;
        return p;
    };
    const size_t slabBytes = (size_t)nbuck * CAP * 4 + 4096; // 8.0 MB (+over-read slack)
    const size_t hBytes    = (size_t)n * 64 * 4;             // 25.6 MB (fp32 h1)
    const size_t gBytes    = (size_t)(n + 1) * 64 * 2;       // 12.8 MB (bf16 g + dummy)
    float*          dinv    = (float*)alloc((size_t)n * 4);
    int*            gcur    = (int*)alloc((size_t)nbuck * 4);
    int2*           rowinfo = (int2*)alloc((size_t)n * 8);
    int*            csr     = (int*)alloc(slabBytes);
    char*           regionA = (char*)alloc(hBytes > slabBytes ? hBytes : slabBytes);
    unsigned short* gBf     = (unsigned short*)alloc(gBytes);
    unsigned* packed = (unsigned*)regionA;   // dead after k_csr
    float*    bufH   = (float*)regionA;      // h1 (fp32), written from agg1 on

    // ---- init (slab cursors + dummy bf16 row) ----
    k_init<<<1, 512, 0, stream>>>(gcur, nbuck, gBf + (size_t)n * 64);

    // ---- slab counting sort -> dst-sorted csr slabs + rowinfo + dinv ----
    k_bsort<<<nchunks, STPB, 0, stream>>>(src, dst, E, nbuck, gcur, packed);
    k_csr<<<nbuck, 512, 0, stream>>>(packed, gcur, n, csr, rowinfo, dinv);

    const int gemmGrid = (n + 63) / 64;
    const int nodeGrid = (n + 15) / 16;      // 4 nodes/wave, 4 waves/block

    // ---- layer 1 ----
    k_gemm64bf<<<gemmGrid, 256, 0, stream>>>(x, W1, dinv, gBf, n);
    k_aggregate<false><<<nodeGrid, 256, 0, stream>>>((const uint4*)gBf, rowinfo, csr,
                                                     dinv, b1, nullptr, nullptr,
                                                     bufH, nullptr, n);
    // ---- layer 2 (head fused into epilogue) ----
    k_gemm64bf<<<gemmGrid, 256, 0, stream>>>(bufH, W2, dinv, gBf, n);
    k_aggregate<true><<<nodeGrid, 256, 0, stream>>>((const uint4*)gBf, rowinfo, csr,
                                                    dinv, b2, Wo, bo,
                                                    nullptr, out, n);
}

// Round 22
// 133.494 us; speedup vs baseline: 1.0400x; 1.0111x over previous
//
#include <hip/hip_runtime.h>

// GCN 2-layer + linear head on MI355X.
// R21 post-mortem: 3rd GEMM-codegen attempt neutral (135.0; VGPR stuck at
// 36) -- GEMM mining stopped. Plateau 136.2->135.0 over 5 rounds.
// R22: widen k_bsort/k_csr to 1024 threads (was 512 at ~1.2-1.5 blocks/CU
// = only 8 waves/CU -- random loads + LDS-atomic chains unhidden). Scan
// helper templated; everything else identical. If <2us: roofline.

typedef float v2f __attribute__((ext_vector_type(2)));

constexpr int NB_SHIFT = 8;                 // 256 nodes per bucket
constexpr int BUCK_NODES = 1 << NB_SHIFT;
constexpr int CAP = 5120;                   // slab cap (max bucket ~3500 + 512 self + pad)
constexpr int CHUNK = 4096;                 // edges per sort block
constexpr int STPB = 1024;                  // sort threads per block (R22: was 512)
// assumes nbuck <= 512, src < 2^17, padded bucket size <= CAP

// ---- init: slab cursors + dummy bf16 row (replaces hipMemsetAsync) -----
__global__ __launch_bounds__(512) void k_init(int* __restrict__ gcur, int nbuck,
                                              unsigned short* __restrict__ dummyRow) {
    int t = threadIdx.x;
    if (t < nbuck) gcur[t] = 0;
    if (t < 64) dummyRow[t] = 0;
}

// inclusive block scan (NT threads) via wave shfl + NT/64-entry LDS; 2 barriers
template <int NT>
__device__ __forceinline__ int blockScanIncl(int v, int tid, int* wsum) {
    constexpr int NW = NT / 64;
    int lane = tid & 63, wv = tid >> 6;
    int inc = v;
#pragma unroll
    for (int s = 1; s < 64; s <<= 1) {
        int t = __shfl_up(inc, s, 64);
        if (lane >= s) inc += t;
    }
    if (lane == 63) wsum[wv] = inc;
    __syncthreads();
    if (wv == 0 && lane < NW) {
        int t = wsum[lane];
#pragma unroll
        for (int s = 1; s < NW; s <<= 1) {
            int u = __shfl_up(t, s, 64);
            if (lane >= s) t += u;
        }
        wsum[lane] = t;
    }
    __syncthreads();
    return (wv > 0) ? inc + wsum[wv - 1] : inc;
}

// ---- fused: chunk histogram -> slab reserve -> LDS sort -> dense flush -
__global__ __launch_bounds__(STPB) void k_bsort(const int* __restrict__ src,
                                                const int* __restrict__ dst, int E, int nbuck,
                                                int* __restrict__ gcur,
                                                unsigned* __restrict__ packed) {
    __shared__ int shStart[STPB];
    __shared__ int shCur[STPB];
    __shared__ int shOff[512];
    __shared__ int wsum[STPB / 64];
    __shared__ unsigned stage[CHUNK];
    __shared__ unsigned short sbkt[CHUNK];
    const int tid = threadIdx.x;
    const int base = blockIdx.x * CHUNK;
    const int end = min(base + CHUNK, E);
    // pass A: count buckets in this chunk (LDS atomics); cache dst in regs
    int myD[CHUNK / STPB];
    shCur[tid] = 0;
    __syncthreads();
    {
        int j = 0;
        for (int e = base + tid; e < end; e += STPB, ++j) {
            int d = dst[e];
            myD[j] = d;
            atomicAdd(&shCur[d >> NB_SHIFT], 1);
        }
    }
    __syncthreads();
    int v = shCur[tid];
    int inc = blockScanIncl<STPB>(v, tid, wsum);  // 2 barriers
    int exc = inc - v;
    shStart[tid] = exc;
    shCur[tid] = exc;
    // reserve this chunk's span in bucket slabs (one global atomic each)
    if (tid < nbuck) shOff[tid] = tid * CAP + ((v > 0) ? atomicAdd(&gcur[tid], v) : 0);
    __syncthreads();
    // pass B: permute chunk into LDS, bucket-major (dst from registers)
    {
        int j = 0;
        for (int e = base + tid; e < end; e += STPB, ++j) {
            int s = src[e];
            int d = myD[j];
            int b = d >> NB_SHIFT;
            int slot = atomicAdd(&shCur[b], 1);
            stage[slot] = ((unsigned)(d & (BUCK_NODES - 1)) << 17) | (unsigned)s;
            sbkt[slot] = (unsigned short)b;
        }
    }
    __syncthreads();
    // pass C: linear flush, same-bucket runs land contiguously
    int cnt = end - base;
    for (int i = tid; i < cnt; i += STPB) {
        int b = sbkt[i];
        packed[shOff[b] + (i - shStart[b])] = stage[i];
    }
}

// ---- per-bucket counting sort by dstLocal -> csr slab; appends SELF edge
//      then pads to x2. rowinfo=(start, paddedCount), dinv ---------------
__global__ __launch_bounds__(1024) void k_csr(const unsigned* __restrict__ packed,
                                              const int* __restrict__ gcur, int n,
                                              int* __restrict__ csr, int2* __restrict__ rowinfo,
                                              float* __restrict__ dinv) {
    __shared__ int cnt[BUCK_NODES];
    __shared__ int cur[BUCK_NODES];
    __shared__ int wsum[16];
    const int tid = threadIdx.x;
    const int e0 = blockIdx.x * CAP;
    const int e1 = e0 + gcur[blockIdx.x];     // slab base + size
    if (tid < BUCK_NODES) cnt[tid] = 0;
    __syncthreads();
    for (int e = e0 + tid; e < e1; e += 1024)
        atomicAdd(&cnt[packed[e] >> 17], 1);
    __syncthreads();
    int v = (tid < BUCK_NODES) ? cnt[tid] : 0;
    int pad = (tid < BUCK_NODES) ? ((v + 2) & ~1) : 0;   // v + self, round x2
    int inc = blockScanIncl<1024>(pad, tid, wsum);  // 2 barriers
    int start = 0;
    if (tid < BUCK_NODES) {
        start = e0 + inc - pad;
        cur[tid] = start;
        int node = blockIdx.x * BUCK_NODES + tid;
        if (node < n) {
            rowinfo[node] = make_int2(start, pad);
            dinv[node] = rsqrtf(1.0f + (float)v);
        }
    }
    __syncthreads();
    for (int e = e0 + tid; e < e1; e += 1024) {
        unsigned p = packed[e];
        int pos = atomicAdd(&cur[p >> 17], 1);   // LDS cursor
        csr[pos] = (int)(p & 0x1FFFFu);          // dense slab window, L2-hot
    }
    __syncthreads();
    // append self edge, then dummy-pad (index n = zero bf16 row)
    if (tid < BUCK_NODES) {
        int node = blockIdx.x * BUCK_NODES + tid;
        csr[start + v] = (node < n) ? node : n;
        for (int p = v + 1; p < pad; ++p) csr[start + p] = n;
    }
}

// ---- GEMM: gBf[i][f] = bf16((sum_k A[i][k] * W[k][f]) * dinv[i]) -------
// A-row pointer via readfirstlane -> SGPR -> scalar s_loads, v_fmac v,s,v.
__global__ __launch_bounds__(256, 1) void k_gemm64bf(const float* __restrict__ A,
                                                     const float* __restrict__ W,
                                                     const float* __restrict__ dinv,
                                                     unsigned short* __restrict__ out,
                                                     int n) {
    const int lane = threadIdx.x & 63;
    const int wave = threadIdx.x >> 6;
    float wcol[64];
#pragma unroll
    for (int k = 0; k < 64; ++k) wcol[k] = W[k * 64 + lane];
#pragma unroll
    for (int k = 0; k < 64; ++k) asm volatile("" : "+v"(wcol[k]));  // pin in VGPRs
    int base = blockIdx.x * 64;
    for (int r = wave; r < 64; r += 4) {
        int row = base + r;
        if (row >= n) break;
        int urow = __builtin_amdgcn_readfirstlane(row);   // SGPR row index
        const float* Ar = A + (size_t)urow * 64;          // uniform -> s_load path
        float acc = 0.0f;
#pragma unroll
        for (int k = 0; k < 64; ++k) acc = fmaf(Ar[k], wcol[k], acc);
        float val = acc * dinv[urow];
        unsigned u = __float_as_uint(val);
        u = (u + 0x7FFFu + ((u >> 16) & 1u)) >> 16;   // RNE to bf16
        out[(size_t)urow * 64 + lane] = (unsigned short)u;
    }
}

__device__ __forceinline__ v2f bf2(unsigned u) {
    v2f r;
    r.x = __uint_as_float(u << 16);
    r.y = __uint_as_float(u & 0xFFFF0000u);
    return r;
}

// ---- Aggregate: FOUR nodes per wave (16 lanes each); bf16 rows ---------
// lane = 16*s + 8*grp + q; 4-deep gather unroll; self-loop in csr.
// Reduce: 1 halving round (mask 8); float4 epilogue (fp32 h1) or head GEMV.
template <bool LAST>
__global__ __launch_bounds__(256) void k_aggregate(
    const uint4* __restrict__ g4,
    const int2* __restrict__ rowinfo, const int* __restrict__ csr,
    const float* __restrict__ dinv, const float* __restrict__ bias,
    const float* __restrict__ Wo, const float* __restrict__ bo,
    float* __restrict__ outRow, float* __restrict__ outHead, int n) {
    int w = (blockIdx.x * blockDim.x + threadIdx.x) >> 6;
    int lane = threadIdx.x & 63;
    const int s = lane >> 4;                  // node slot 0..3
    const int grp = (lane >> 3) & 1;          // 0..1
    const int q = lane & 7;                   // 0..7
    int node = 4 * w + s;
    const bool valid = node < n;
    int2 ri = valid ? rowinfo[node] : make_int2(0, 0);
    const int e = ri.x;
    const int rnds = ri.y >> 1;
    int rm = rnds;
    rm = max(rm, __shfl_xor(rm, 16, 64));
    rm = max(rm, __shfl_xor(rm, 32, 64));     // max over 4 slots
    v2f a0v = {0.f, 0.f}, a1v = {0.f, 0.f}, a2v = {0.f, 0.f}, a3v = {0.f, 0.f};
    int r = 0;
    for (; r + 4 <= rm; r += 4) {             // 32 edge-rows in flight / wave
        int c0 = csr[e + 2 * r + grp];        // shared base + imm offsets
        int c1 = csr[e + 2 * r + 2 + grp];
        int c2 = csr[e + 2 * r + 4 + grp];
        int c3 = csr[e + 2 * r + 6 + grp];
        int i0 = (r < rnds) ? c0 : n;
        int i1 = (r + 1 < rnds) ? c1 : n;
        int i2 = (r + 2 < rnds) ? c2 : n;
        int i3 = (r + 3 < rnds) ? c3 : n;
        uint4 x0 = g4[(size_t)i0 * 8 + q];
        uint4 x1 = g4[(size_t)i1 * 8 + q];
        uint4 x2 = g4[(size_t)i2 * 8 + q];
        uint4 x3 = g4[(size_t)i3 * 8 + q];
        a0v += bf2(x0.x); a1v += bf2(x0.y); a2v += bf2(x0.z); a3v += bf2(x0.w);
        a0v += bf2(x1.x); a1v += bf2(x1.y); a2v += bf2(x1.z); a3v += bf2(x1.w);
        a0v += bf2(x2.x); a1v += bf2(x2.y); a2v += bf2(x2.z); a3v += bf2(x2.w);
        a0v += bf2(x3.x); a1v += bf2(x3.y); a2v += bf2(x3.z); a3v += bf2(x3.w);
    }
    for (; r < rm; ++r) {                     // tail (<=3 rounds)
        int c0 = csr[e + 2 * r + grp];
        int i0 = (r < rnds) ? c0 : n;
        uint4 x0 = g4[(size_t)i0 * 8 + q];
        a0v += bf2(x0.x); a1v += bf2(x0.y); a2v += bf2(x0.z); a3v += bf2(x0.w);
    }
    // one halving round over grp (mask 8): grp0 ends with feat 8q..8q+3,
    // grp1 with 8q+4..8q+7
    v2f keep0 = grp ? a2v : a0v;
    v2f keep1 = grp ? a3v : a1v;
    v2f send0 = grp ? a0v : a2v;
    v2f send1 = grp ? a1v : a3v;
    keep0.x += __shfl_xor(send0.x, 8, 64);
    keep0.y += __shfl_xor(send0.y, 8, 64);
    keep1.x += __shfl_xor(send1.x, 8, 64);
    keep1.y += __shfl_xor(send1.y, 8, 64);
    const int base = 8 * q + 4 * grp;
    float dv = valid ? dinv[node] : 0.f;
    float4 bb = *(const float4*)&bias[base];
    float4 vv;
    vv.x = fmaxf(fmaf(dv, keep0.x, bb.x), 0.f);
    vv.y = fmaxf(fmaf(dv, keep0.y, bb.y), 0.f);
    vv.z = fmaxf(fmaf(dv, keep1.x, bb.z), 0.f);
    vv.w = fmaxf(fmaf(dv, keep1.y, bb.w), 0.f);
    if constexpr (LAST) {
        float4 ww = *(const float4*)&Wo[base];
        float p = vv.x * ww.x + vv.y * ww.y + vv.z * ww.z + vv.w * ww.w;
#pragma unroll
        for (int m = 1; m <= 8; m <<= 1) p += __shfl_xor(p, m, 64);
        if ((lane & 15) == 0 && valid) outHead[node] = p + bo[0];
    } else {
        if (valid) *(float4*)&outRow[(size_t)node * 64 + base] = vv;
    }
}

extern "C" void kernel_launch(void* const* d_in, const int* in_sizes, int n_in,
                              void* d_out, int out_size, void* d_ws, size_t ws_size,
                              hipStream_t stream) {
    const float* x  = (const float*)d_in[0];
    const int*   ei = (const int*)d_in[1];
    const float* W1 = (const float*)d_in[2];
    const float* b1 = (const float*)d_in[3];
    const float* W2 = (const float*)d_in[4];
    const float* b2 = (const float*)d_in[5];
    const float* Wo = (const float*)d_in[6];
    const float* bo = (const float*)d_in[7];
    float* out = (float*)d_out;

    const int n = in_sizes[0] / 64;
    const int E = in_sizes[1] / 2;
    const int* src = ei;
    const int* dst = ei + E;

    const int nbuck = (n + BUCK_NODES - 1) >> NB_SHIFT;      // 391
    const int nchunks = (E + CHUNK - 1) / CHUNK;             // 306

    char* ws = (char*)d_ws;
    size_t off = 0;
    auto alloc = [&](size_t bytes) -> void* {
        void* p = ws + off;
        off += (bytes + 255) & ~(size_t)255;
        return p;
    };
    const size_t slabBytes = (size_t)nbuck * CAP * 4 + 4096; // 8.0 MB (+over-read slack)
    const size_t hBytes    = (size_t)n * 64 * 4;             // 25.6 MB (fp32 h1)
    const size_t gBytes    = (size_t)(n + 1) * 64 * 2;       // 12.8 MB (bf16 g + dummy)
    float*          dinv    = (float*)alloc((size_t)n * 4);
    int*            gcur    = (int*)alloc((size_t)nbuck * 4);
    int2*           rowinfo = (int2*)alloc((size_t)n * 8);
    int*            csr     = (int*)alloc(slabBytes);
    char*           regionA = (char*)alloc(hBytes > slabBytes ? hBytes : slabBytes);
    unsigned short* gBf     = (unsigned short*)alloc(gBytes);
    unsigned* packed = (unsigned*)regionA;   // dead after k_csr
    float*    bufH   = (float*)regionA;      // h1 (fp32), written from agg1 on

    // ---- init (slab cursors + dummy bf16 row) ----
    k_init<<<1, 512, 0, stream>>>(gcur, nbuck, gBf + (size_t)n * 64);

    // ---- slab counting sort -> dst-sorted csr slabs + rowinfo + dinv ----
    k_bsort<<<nchunks, STPB, 0, stream>>>(src, dst, E, nbuck, gcur, packed);
    k_csr<<<nbuck, 1024, 0, stream>>>(packed, gcur, n, csr, rowinfo, dinv);

    const int gemmGrid = (n + 63) / 64;
    const int nodeGrid = (n + 15) / 16;      // 4 nodes/wave, 4 waves/block

    // ---- layer 1 ----
    k_gemm64bf<<<gemmGrid, 256, 0, stream>>>(x, W1, dinv, gBf, n);
    k_aggregate<false><<<nodeGrid, 256, 0, stream>>>((const uint4*)gBf, rowinfo, csr,
                                                     dinv, b1, nullptr, nullptr,
                                                     bufH, nullptr, n);
    // ---- layer 2 (head fused into epilogue) ----
    k_gemm64bf<<<gemmGrid, 256, 0, stream>>>(bufH, W2, dinv, gBf, n);
    k_aggregate<true><<<nodeGrid, 256, 0, stream>>>((const uint4*)gBf, rowinfo, csr,
                                                    dinv, b2, Wo, bo,
                                                    nullptr, out, n);
}